// Round 6
// baseline (510.279 us; speedup 1.0000x reference)
//
#include <hip/hip_runtime.h>

#define KSEG 10000
#define NBLK 512          // sort blocks; chunk = 15625 <= 16384 -> u16 records, 2 blocks/CU
#define CHUNKMAX 16384    // rec16 capacity (15 bits local_j headroom: 14 bits used + ev)
#define GBIN 3            // bins per runsort block (~38 KB LDS -> 4 blocks/CU)
#define CAPE 3072         // runsort staging capacity (3-bin mean 2400, +13 sigma)

typedef unsigned long long u64;
typedef unsigned int u32;
typedef unsigned short u16;
typedef unsigned char u8;

// ---------------- fused: hist + per-block scan + one-phase u16 LDS counting scatter ------
// Record = (local_j<<1)|ev fits u16 (chunk <= 16384). LDS: poolA 40 KB (h32 overlay /
// rec16) + cp 20 KB = ~59 KB -> 2 blocks/CU (32 waves): scan/atomic phases of one block
// overlap streaming phases of the co-resident block.
__global__ __launch_bounds__(1024) void localsort_lds(const int* __restrict__ dur,
                                                      const float* __restrict__ log_h,
                                                      const int* __restrict__ events,
                                                      u64* __restrict__ S,
                                                      u16* __restrict__ Pb,
                                                      int N, int chunk) {
    __shared__ u32 poolA[KSEG];          // 40000 B: h32 (pass1/scan), rec16 (scatter/dump)
    __shared__ u32 cp[KSEG / 2];         // 20000 B packed dual-u16 cursors
    __shared__ u32 wsum[16];
    __shared__ u32 carry_s;
    u32* h32 = poolA;
    u16* rec16 = (u16*)poolA;            // 32768 B < 40000 B, h32 dead before first write

    int b = blockIdx.x;
    int s = b * chunk, e = min(N, s + chunk);
    int tid = threadIdx.x;
    int lane = tid & 63, wid = tid >> 6;
    int kiter = (chunk + 1023) >> 10;    // 16 for N=8M (<=32 so myev bitmask fits u32)

    for (int i = tid; i < KSEG; i += 1024) h32[i] = 0;
    if (tid == 0) carry_s = 0;
    __syncthreads();

    // ---- pass 1: histogram; events -> register bitmask ----
    u32 myev = 0;
    for (int k = 0; k < kiter; ++k) {
        int j = s + tid + (k << 10);
        if (j < e) {
            int d = dur[j];
            myev |= (u32)(events[j] & 1) << k;
            atomicAdd(&h32[d], 1);
        }
    }
    __syncthreads();

    // ---- exclusive scan over KSEG bins (strips of 1024, wave-shuffle scan) ----
    for (int base = 0; base < KSEG; base += 1024) {
        int t = base + tid;
        u32 h = (t < KSEG) ? h32[t] : 0;
        u32 v = h;
        for (int off = 1; off < 64; off <<= 1) {
            u32 x = __shfl_up(v, off);
            if (lane >= off) v += x;
        }
        if (lane == 63) wsum[wid] = v;
        __syncthreads();
        if (wid == 0) {
            u32 wv = (lane < 16) ? wsum[lane] : 0;
            for (int off = 1; off < 16; off <<= 1) {
                u32 x = __shfl_up(wv, off);
                if (lane >= off) wv += x;
            }
            if (lane < 16) wsum[lane] = wv;
        }
        __syncthreads();
        u32 incl = v + ((wid > 0) ? wsum[wid - 1] : 0) + carry_s;
        u32 excl = incl - h;
        if (t < KSEG) {
            Pb[(size_t)b * (KSEG + 1) + t] = (u16)excl;
            if (!(t & 1)) cp[t >> 1] = excl | (incl << 16);  // excl_t | excl_{t+1}<<16
        }
        __syncthreads();
        if (tid == 1023) carry_s = incl;
    }
    __syncthreads();
    u32 total = carry_s;
    if (tid == 0) Pb[(size_t)b * (KSEG + 1) + KSEG] = (u16)total;
    __syncthreads();

    // ---- single scatter phase: u16 records (dur re-read, L2-warm) ----
    for (int k = 0; k < kiter; ++k) {
        int j = s + tid + (k << 10);
        if (j < e) {
            int d = dur[j];
            u32 add = (d & 1) ? 0x10000u : 1u;
            u32 old = atomicAdd(&cp[d >> 1], add);
            u32 pos = (d & 1) ? (old >> 16) : (old & 0xffffu);
            rec16[pos] = (u16)((u32)((tid + (k << 10)) << 1) | ((myev >> k) & 1u));
        }
    }
    __syncthreads();

    // ---- coalesced dump: reconstruct u64 records; log_h gather in 62.5 KB window ----
    for (u32 i = tid; i < total; i += 1024) {
        u32 v = rec16[i];
        int j = s + (int)(v >> 1);
        u32 hi = ((u32)j << 1) | (v & 1u);
        S[(size_t)s + i] = ((u64)hi << 32) | (u64)__float_as_uint(log_h[j]);
    }
}

// ---------------- transpose Pb[NBLK][K+1] -> PbT[K+1][NBLK] ----------------
__global__ void transpose_pb(const u16* __restrict__ Pb, u16* __restrict__ PbT) {
    __shared__ u16 tile[64][65];
    int t0 = blockIdx.x * 64;
    int b0 = blockIdx.y * 64;
    int tx = threadIdx.x;        // 0..63
    int ty = threadIdx.y;        // 0..3
    for (int r = ty; r < 64; r += 4) {
        int b = b0 + r, t = t0 + tx;
        tile[r][tx] = (b < NBLK && t <= KSEG) ? Pb[(size_t)b * (KSEG + 1) + t] : (u16)0;
    }
    __syncthreads();
    for (int r = ty; r < 64; r += 4) {
        int t = t0 + r, b = b0 + tx;
        if (t <= KSEG && b < NBLK) PbT[(size_t)t * NBLK + b] = tile[tx][r];
    }
}

// ---------------- cum[t] = sum_b Pb[b][t] (sum of per-block EXCLUSIVE prefixes IS the
// global exclusive prefix). One wave per PbT row: uint4/lane covers 512 u16 exactly. ----
__global__ __launch_bounds__(256) void cum_rows(const u16* __restrict__ PbT,
                                                int* __restrict__ cum) {
    int r = blockIdx.x * 4 + (threadIdx.x >> 6);
    if (r > KSEG) return;
    int lane = threadIdx.x & 63;
    const uint4* row = (const uint4*)(PbT + (size_t)r * NBLK);  // 64 uint4 = 512 u16
    uint4 v = row[lane];
    int sum = (int)(v.x & 0xffff) + (int)(v.x >> 16) + (int)(v.y & 0xffff) + (int)(v.y >> 16)
            + (int)(v.z & 0xffff) + (int)(v.z >> 16) + (int)(v.w & 0xffff) + (int)(v.w >> 16);
    for (int off = 32; off > 0; off >>= 1) sum += __shfl_down(sum, off);
    if (lane == 0) cum[r] = sum;
}

// ---------------- element-parallel runsort over 512 source blocks ----------
// pair = (bin tt, src block bb), id = tt*512+bb (<1536, u16). Runs mean 1.56.
// LDS ~38 KB -> 4 blocks/CU. Phase D bin lookup is pid[x]>>9.
__global__ __launch_bounds__(512, 8) void runsort_ep(const u64* __restrict__ S,
                                                     const int* __restrict__ cum,
                                                     const u16* __restrict__ PbT,
                                                     float* __restrict__ P,
                                                     u32* __restrict__ J,
                                                     u32* __restrict__ E2w,
                                                     u16* __restrict__ binhint,
                                                     int N, int chunk) {
    __shared__ u64 sm[CAPE];                 // 24576 B staging
    __shared__ u16 pid[CAPE];                // 6144 B: element -> pair id
    __shared__ u16 ofs[GBIN * NBLK];         // 3072 B: scanned run offsets (1536 entries)
    __shared__ u16 rows[(GBIN + 1) * NBLK];  // 4096 B: PbT rows (absolute per-block offsets)
    __shared__ u32 bitsSh[CAPE / 32];        // 384 B: batch-wide event bits (desc-relative)
    __shared__ u32 wpart[8];
    __shared__ int cumLoc[GBIN + 1];

    int t0 = blockIdx.x * GBIN;
    int G2 = min(GBIN, KSEG - t0);
    if (G2 <= 0) return;
    int tid = threadIdx.x;
    int lane = tid & 63, wid = tid >> 6;

    for (int i = tid; i < (G2 + 1) * NBLK; i += 512) {
        int t = i >> 9, b = i & (NBLK - 1);
        rows[i] = PbT[(size_t)(t0 + t) * NBLK + b];
    }
    if (tid <= G2) cumLoc[tid] = cum[t0 + tid];
    __syncthreads();

    int u = 0;
    while (u < G2) {
        int m = 1;
        while (u + m < G2 && cumLoc[u + m + 1] - cumLoc[u] <= CAPE) ++m;
        int aBatch = cumLoc[u];
        int tot = cumLoc[u + m] - aBatch;
        int descbase = N - cumLoc[u + m];

        // ---- run lengths (3/thread chains) + exclusive scan -> ofs (u16) ----
        int base3 = tid * 3;
        int r3[3];
        int sum3 = 0;
        for (int k = 0; k < 3; ++k) {
            int idx = base3 + k;
            int tt = idx >> 9, bb = idx & (NBLK - 1);
            int lk = (tt < m)
                   ? (int)rows[(u + tt + 1) * NBLK + bb] - (int)rows[(u + tt) * NBLK + bb]
                   : 0;
            r3[k] = sum3;
            sum3 += lk;
        }
        int v = sum3;
        for (int off = 1; off < 64; off <<= 1) {
            int x = __shfl_up(v, off);
            if (lane >= off) v += x;
        }
        if (lane == 63) wpart[wid] = (u32)v;
        __syncthreads();
        if (tid == 0) {
            u32 run = 0;
            for (int w = 0; w < 8; ++w) { u32 tmp = wpart[w]; wpart[w] = run; run += tmp; }
        }
        __syncthreads();
        {
            int excl3 = v - sum3 + (int)wpart[wid];
            for (int k = 0; k < 3; ++k) ofs[base3 + k] = (u16)(excl3 + r3[k]);
        }
        __syncthreads();

        // ---- phase A: pair-owner writes pid (tiny LDS writes) + zero event bits ----
        for (int i = tid; i < m * NBLK; i += 512) {
            int tt = i >> 9, bb = i & (NBLK - 1);
            int l = (int)rows[(u + tt + 1) * NBLK + bb] - (int)rows[(u + tt) * NBLK + bb];
            int o = (int)ofs[i];
            for (int k = 0; k < l; ++k) pid[o + k] = (u16)i;
        }
        {
            int nw = (tot + 31) >> 5;
            for (int k = tid; k < nw; k += 512) bitsSh[k] = 0;
        }
        __syncthreads();

        // ---- phase B: element-parallel gather (independent 8B loads, high MLP) ----
        for (int x = tid; x < tot; x += 512) {
            int p = (int)pid[x];
            int tt = p >> 9, bb = p & (NBLK - 1);
            int r0 = (int)rows[(u + tt) * NBLK + bb];
            int k = x - (int)ofs[p];
            sm[x] = S[(size_t)bb * chunk + r0 + k];
        }
        __syncthreads();

        // ---- phase C: pair-parallel insertion sort of LDS-resident runs ----
        for (int i = tid; i < m * NBLK; i += 512) {
            int tt = i >> 9, bb = i & (NBLK - 1);
            int l = (int)rows[(u + tt + 1) * NBLK + bb] - (int)rows[(u + tt) * NBLK + bb];
            int o = (int)ofs[i];
            for (int k = 1; k < l; ++k) {
                u64 key = sm[o + k];
                int jj = o + k - 1;
                while (jj >= o && sm[jj] > key) { sm[jj + 1] = sm[jj]; --jj; }
                sm[jj + 1] = key;
            }
        }
        __syncthreads();

        // ---- phase D: batch-wide emit (J coalesced; P run-coalesced; bits to LDS) ----
        for (int x = tid; x < tot; x += 512) {
            int lt = (int)pid[x] >> 9;                       // batch-local bin, no search
            u64 rec = sm[x];
            int i_in = x - (cumLoc[u + lt] - aBatch);
            int descpos = N - cumLoc[u + lt + 1] + i_in;
            P[descpos] = expf(__uint_as_float((u32)rec));
            J[aBatch + x] = (u32)(rec >> 33);
            if (rec & 0x100000000ull) {
                int bi = descpos - descbase;
                atomicOr(&bitsSh[bi >> 5], 1u << (bi & 31));
            }
        }
        // binhint for every 256-boundary inside this batch (global bin id)
        {
            int k0 = (aBatch + 255) >> 8;
            int k1e = cumLoc[u + m];
            for (int kk = k0 + tid; (kk << 8) < k1e; kk += 512) {
                int p = kk << 8;
                int lt = 0;
                while (p >= cumLoc[u + lt + 1]) ++lt;
                binhint[kk] = (u16)(t0 + u + lt);
            }
        }
        __syncthreads();

        // ---- flush event bits to global (edge words shared across blocks -> atomicOr) ----
        {
            int nw = (tot + 31) >> 5;
            for (int k = tid; k < nw; k += 512) {
                u32 vv = bitsSh[k];
                if (!vv) continue;
                long gb = (long)descbase + 32l * k;
                int w = (int)(gb >> 5), sh = (int)(gb & 31);
                atomicOr(&E2w[w], vv << sh);
                if (sh && (vv >> (32 - sh))) atomicOr(&E2w[w + 1], vv >> (32 - sh));
            }
        }
        __syncthreads();
        u += m;
    }
}

// ---------------- segment sums (faithful cross-indexing): keyed by dur[j], summand P[j] ----
// grid = NBLK = 512 -> 80 KB LDS x 2 blocks/CU (latency hiding for the atomic pass).
__global__ __launch_bounds__(1024) void sums3(const int* __restrict__ dur,
                                              const float* __restrict__ P,
                                              const u32* __restrict__ E2w,
                                              float* __restrict__ expg_part,
                                              u16* __restrict__ evs_part,
                                              int N, int chunk) {
    __shared__ float he[KSEG];
    __shared__ int hv[KSEG];
    for (int i = threadIdx.x; i < KSEG; i += blockDim.x) { he[i] = 0.f; hv[i] = 0; }
    __syncthreads();
    int b = blockIdx.x;
    int s = b * chunk, e = min(N, s + chunk);
    for (int j = s + threadIdx.x; j < e; j += blockDim.x) {
        int t = dur[j];
        atomicAdd(&he[t], P[j]);
        if ((E2w[j >> 5] >> (j & 31)) & 1u) atomicAdd(&hv[t], 1);
    }
    __syncthreads();
    for (int i = threadIdx.x; i < KSEG; i += blockDim.x) {
        expg_part[(size_t)b * KSEG + i] = he[i];
        evs_part[(size_t)b * KSEG + i] = (u16)hv[i];
    }
}

__global__ void reduce_sums(const float* __restrict__ expg_part,
                            const u16* __restrict__ evs_part,
                            float* __restrict__ expg, float* __restrict__ evs, int B) {
    int t = blockIdx.x * blockDim.x + threadIdx.x;
    if (t >= KSEG) return;
    float a = 0.f;
    int v = 0;
    for (int b = 0; b < B; ++b) {
        a += expg_part[(size_t)b * KSEG + t];
        v += (int)evs_part[(size_t)b * KSEG + t];
    }
    expg[t] = a;
    evs[t] = (float)v;
}

// ---------------- risk suffix-sum + baseline hazard + total events (wave-shuffle) --------
__global__ __launch_bounds__(1024) void baseline_kernel(const float* __restrict__ expg,
                                                        const float* __restrict__ evs,
                                                        float* __restrict__ base,
                                                        float* __restrict__ ev_total, int K) {
    __shared__ float fwsum[16];
    __shared__ float carry_s;
    int tid = threadIdx.x, lane = tid & 63, wid = tid >> 6;
    if (tid == 0) carry_s = 0.f;
    float evloc = 0.f;
    __syncthreads();
    for (int b = 0; b < K; b += 1024) {
        int u = b + tid;
        int t = K - 1 - u;
        float h = 0.f, ev = 0.f;
        if (u < K) { h = expg[t]; ev = evs[t]; }
        evloc += ev;
        float v = h;
        for (int off = 1; off < 64; off <<= 1) {
            float x = __shfl_up(v, off);
            if (lane >= off) v += x;
        }
        if (lane == 63) fwsum[wid] = v;
        __syncthreads();
        if (wid == 0) {
            float wv = (lane < 16) ? fwsum[lane] : 0.f;
            for (int off = 1; off < 16; off <<= 1) {
                float x = __shfl_up(wv, off);
                if (lane >= off) wv += x;
            }
            if (lane < 16) fwsum[lane] = wv;
        }
        __syncthreads();
        float risk = v + ((wid > 0) ? fwsum[wid - 1] : 0.f) + carry_s;  // inclusive suffix
        if (u < K) base[t] = (risk > 0.f) ? ev / risk : 0.f;
        __syncthreads();
        if (tid == 1023) carry_s = risk;
    }
    // total events: wave reduce + cross-wave
    for (int off = 32; off > 0; off >>= 1) evloc += __shfl_down(evloc, off);
    __syncthreads();
    if (lane == 0) fwsum[wid] = evloc;
    __syncthreads();
    if (tid == 0) {
        float st = 0.f;
        for (int w = 0; w < 16; ++w) st += fwsum[w];
        ev_total[0] = st;
    }
}

// ---------------- MSE, flat grid-stride: (base[t(i)]*P[i] - E2bit[J[i]])^2 ----------------
__global__ __launch_bounds__(1024) void mse4(const float* __restrict__ P,
                                             const u32* __restrict__ J,
                                             const u32* __restrict__ E2w,
                                             const int* __restrict__ cum,
                                             const u16* __restrict__ binhint,
                                             const float* __restrict__ base,
                                             double* __restrict__ acc, int N) {
    int stride = gridDim.x * blockDim.x;
    double s = 0.0;
    for (int i = blockIdx.x * blockDim.x + threadIdx.x; i < N; i += stride) {
        int t = (int)binhint[i >> 8];
        while (cum[t + 1] <= i) ++t;
        u32 x = J[i];
        float ev = (float)((E2w[x >> 5] >> (x & 31)) & 1u);
        float d = base[t] * P[i] - ev;
        s += (double)d * (double)d;
    }
    __shared__ double sm[1024];
    sm[threadIdx.x] = s;
    __syncthreads();
    for (int o = 512; o > 0; o >>= 1) {
        if ((int)threadIdx.x < o) sm[threadIdx.x] += sm[threadIdx.x + o];
        __syncthreads();
    }
    if (threadIdx.x == 0) atomicAdd(acc, sm[0]);
}

__global__ void final_kernel(const double* __restrict__ acc, const float* __restrict__ ev_total,
                             float* __restrict__ out, int N) {
    out[0] = (ev_total[0] == 0.f) ? 0.0f : (float)(*acc / (double)N);
}

extern "C" void kernel_launch(void* const* d_in, const int* in_sizes, int n_in,
                              void* d_out, int out_size, void* d_ws, size_t ws_size,
                              hipStream_t stream) {
    const float* log_h = (const float*)d_in[0];
    const int* dur     = (const int*)d_in[1];
    const int* events  = (const int*)d_in[2];
    int N = in_sizes[0];
    float* out = (float*)d_out;

    char* ws = (char*)d_ws;
    size_t off = 0;
    auto alloc = [&](size_t bytes) -> char* {
        char* p = ws + off;
        off = (off + bytes + 255) & ~(size_t)255;
        return p;
    };
    double* acc  = (double*)alloc(8);
    u32*    E2w  = (u32*)alloc(((size_t)N / 32 + 2) * 4);   // event bitfield (desc-indexed)
    size_t zero_bytes = off;                                 // acc + E2w must start at 0
    float*  ev_total = (float*)alloc(4);
    int*    cum      = (int*)alloc((KSEG + 1) * 4);
    float*  expg     = (float*)alloc(KSEG * 4);
    float*  evs      = (float*)alloc(KSEG * 4);
    float*  base     = (float*)alloc(KSEG * 4);
    u16*    binhint  = (u16*)alloc(((size_t)N / 256 + 1) * 2);
    u16*    Pb       = (u16*)alloc((size_t)NBLK * (KSEG + 1) * 2);
    u16*    PbT      = (u16*)alloc((size_t)(KSEG + 1) * NBLK * 2);
    u64*    S        = (u64*)alloc((size_t)N * 8);
    float*  P        = (float*)alloc((size_t)N * 4);
    u32*    J        = (u32*)alloc((size_t)N * 4);
    (void)ws_size;

    // sums partials alias S (dead after runsort_ep; mse4 uses P/J, not S)
    float* expg_part = (float*)S;                            // 512*10000*4 = 20.5 MB
    u16*   evs_part  = (u16*)((char*)S + (size_t)NBLK * KSEG * 4 + 256);  // +10.2 MB < 64 MB

    int chunk = (N + NBLK - 1) / NBLK;   // 15625 <= CHUNKMAX -> u16 records valid

    hipMemsetAsync(d_ws, 0, zero_bytes, stream);

    localsort_lds<<<NBLK, 1024, 0, stream>>>(dur, log_h, events, S, Pb, N, chunk);
    transpose_pb<<<dim3((KSEG + 64) / 64, NBLK / 64), dim3(64, 4), 0, stream>>>(Pb, PbT);
    cum_rows<<<(KSEG + 4) / 4, 256, 0, stream>>>(PbT, cum);
    runsort_ep<<<(KSEG + GBIN - 1) / GBIN, 512, 0, stream>>>(S, cum, PbT, P, J, E2w,
                                                             binhint, N, chunk);
    sums3<<<NBLK, 1024, 0, stream>>>(dur, P, E2w, expg_part, evs_part, N, chunk);
    reduce_sums<<<(KSEG + 255) / 256, 256, 0, stream>>>(expg_part, evs_part, expg, evs, NBLK);
    baseline_kernel<<<1, 1024, 0, stream>>>(expg, evs, base, ev_total, KSEG);
    mse4<<<512, 1024, 0, stream>>>(P, J, E2w, cum, binhint, base, acc, N);
    final_kernel<<<1, 1, 0, stream>>>(acc, ev_total, out, N);
}

// Round 7
// 399.796 us; speedup vs baseline: 1.2764x; 1.2764x over previous
//
#include <hip/hip_runtime.h>

#define KSEG 10000
#define NBLK 512          // sort blocks; chunk = 15625 <= 16384 -> u16 records, 2 blocks/CU
#define CHUNKMAX 16384    // rec16 capacity (15 bits local_j headroom: 14 bits used + ev)
#define GBIN 3            // bins per runsort block (~38 KB LDS -> 4 blocks/CU)
#define CAPE 3072         // runsort staging capacity (3-bin mean 2400, +13 sigma)

typedef unsigned long long u64;
typedef unsigned int u32;
typedef unsigned short u16;
typedef unsigned char u8;

// ---------------- fused: hist + per-block scan + one-phase u16 LDS counting scatter ------
// Record = (local_j<<1)|ev fits u16 (chunk <= 16384). LDS: poolA 40 KB (h32 overlay /
// rec16) + cp 20 KB = ~59 KB -> 2 blocks/CU (32 waves): scan/atomic phases of one block
// overlap streaming phases of the co-resident block.
__global__ __launch_bounds__(1024) void localsort_lds(const int* __restrict__ dur,
                                                      const float* __restrict__ log_h,
                                                      const int* __restrict__ events,
                                                      u64* __restrict__ S,
                                                      u16* __restrict__ Pb,
                                                      int N, int chunk) {
    __shared__ u32 poolA[KSEG];          // 40000 B: h32 (pass1/scan), rec16 (scatter/dump)
    __shared__ u32 cp[KSEG / 2];         // 20000 B packed dual-u16 cursors
    __shared__ u32 wsum[16];
    __shared__ u32 carry_s;
    u32* h32 = poolA;
    u16* rec16 = (u16*)poolA;            // 32768 B < 40000 B, h32 dead before first write

    int b = blockIdx.x;
    int s = b * chunk, e = min(N, s + chunk);
    int tid = threadIdx.x;
    int lane = tid & 63, wid = tid >> 6;
    int kiter = (chunk + 1023) >> 10;    // 16 for N=8M (<=32 so myev bitmask fits u32)

    for (int i = tid; i < KSEG; i += 1024) h32[i] = 0;
    if (tid == 0) carry_s = 0;
    __syncthreads();

    // ---- pass 1: histogram; events -> register bitmask ----
    u32 myev = 0;
    for (int k = 0; k < kiter; ++k) {
        int j = s + tid + (k << 10);
        if (j < e) {
            int d = dur[j];
            myev |= (u32)(events[j] & 1) << k;
            atomicAdd(&h32[d], 1);
        }
    }
    __syncthreads();

    // ---- exclusive scan over KSEG bins (strips of 1024, wave-shuffle scan) ----
    for (int base = 0; base < KSEG; base += 1024) {
        int t = base + tid;
        u32 h = (t < KSEG) ? h32[t] : 0;
        u32 v = h;
        for (int off = 1; off < 64; off <<= 1) {
            u32 x = __shfl_up(v, off);
            if (lane >= off) v += x;
        }
        if (lane == 63) wsum[wid] = v;
        __syncthreads();
        if (wid == 0) {
            u32 wv = (lane < 16) ? wsum[lane] : 0;
            for (int off = 1; off < 16; off <<= 1) {
                u32 x = __shfl_up(wv, off);
                if (lane >= off) wv += x;
            }
            if (lane < 16) wsum[lane] = wv;
        }
        __syncthreads();
        u32 incl = v + ((wid > 0) ? wsum[wid - 1] : 0) + carry_s;
        u32 excl = incl - h;
        if (t < KSEG) {
            Pb[(size_t)b * (KSEG + 1) + t] = (u16)excl;
            if (!(t & 1)) cp[t >> 1] = excl | (incl << 16);  // excl_t | excl_{t+1}<<16
        }
        __syncthreads();
        if (tid == 1023) carry_s = incl;
    }
    __syncthreads();
    u32 total = carry_s;
    if (tid == 0) Pb[(size_t)b * (KSEG + 1) + KSEG] = (u16)total;
    __syncthreads();

    // ---- single scatter phase: u16 records (dur re-read, L2-warm) ----
    for (int k = 0; k < kiter; ++k) {
        int j = s + tid + (k << 10);
        if (j < e) {
            int d = dur[j];
            u32 add = (d & 1) ? 0x10000u : 1u;
            u32 old = atomicAdd(&cp[d >> 1], add);
            u32 pos = (d & 1) ? (old >> 16) : (old & 0xffffu);
            rec16[pos] = (u16)((u32)((tid + (k << 10)) << 1) | ((myev >> k) & 1u));
        }
    }
    __syncthreads();

    // ---- coalesced dump: reconstruct u64 records; log_h gather in 62.5 KB window ----
    for (u32 i = tid; i < total; i += 1024) {
        u32 v = rec16[i];
        int j = s + (int)(v >> 1);
        u32 hi = ((u32)j << 1) | (v & 1u);
        S[(size_t)s + i] = ((u64)hi << 32) | (u64)__float_as_uint(log_h[j]);
    }
}

// ---------------- transpose Pb[NBLK][K+1] -> PbT[K+1][NBLK] ----------------
__global__ void transpose_pb(const u16* __restrict__ Pb, u16* __restrict__ PbT) {
    __shared__ u16 tile[64][65];
    int t0 = blockIdx.x * 64;
    int b0 = blockIdx.y * 64;
    int tx = threadIdx.x;        // 0..63
    int ty = threadIdx.y;        // 0..3
    for (int r = ty; r < 64; r += 4) {
        int b = b0 + r, t = t0 + tx;
        tile[r][tx] = (b < NBLK && t <= KSEG) ? Pb[(size_t)b * (KSEG + 1) + t] : (u16)0;
    }
    __syncthreads();
    for (int r = ty; r < 64; r += 4) {
        int t = t0 + r, b = b0 + tx;
        if (t <= KSEG && b < NBLK) PbT[(size_t)t * NBLK + b] = tile[tx][r];
    }
}

// ---------------- cum[t] = sum_b Pb[b][t] (sum of per-block EXCLUSIVE prefixes IS the
// global exclusive prefix). One wave per PbT row: uint4/lane covers 512 u16 exactly. ----
__global__ __launch_bounds__(256) void cum_rows(const u16* __restrict__ PbT,
                                                int* __restrict__ cum) {
    int r = blockIdx.x * 4 + (threadIdx.x >> 6);
    if (r > KSEG) return;
    int lane = threadIdx.x & 63;
    const uint4* row = (const uint4*)(PbT + (size_t)r * NBLK);  // 64 uint4 = 512 u16
    uint4 v = row[lane];
    int sum = (int)(v.x & 0xffff) + (int)(v.x >> 16) + (int)(v.y & 0xffff) + (int)(v.y >> 16)
            + (int)(v.z & 0xffff) + (int)(v.z >> 16) + (int)(v.w & 0xffff) + (int)(v.w >> 16);
    for (int off = 32; off > 0; off >>= 1) sum += __shfl_down(sum, off);
    if (lane == 0) cum[r] = sum;
}

// ---------------- element-parallel runsort over 512 source blocks ----------
// pair = (bin tt, src block bb), id = tt*512+bb (<1536, u16). Runs mean 1.56.
// LDS ~38 KB -> 4 blocks/CU. Phase D bin lookup is pid[x]>>9.
__global__ __launch_bounds__(512, 8) void runsort_ep(const u64* __restrict__ S,
                                                     const int* __restrict__ cum,
                                                     const u16* __restrict__ PbT,
                                                     float* __restrict__ P,
                                                     u32* __restrict__ J,
                                                     u32* __restrict__ E2w,
                                                     u16* __restrict__ binhint,
                                                     int N, int chunk) {
    __shared__ u64 sm[CAPE];                 // 24576 B staging
    __shared__ u16 pid[CAPE];                // 6144 B: element -> pair id
    __shared__ u16 ofs[GBIN * NBLK];         // 3072 B: scanned run offsets (1536 entries)
    __shared__ u16 rows[(GBIN + 1) * NBLK];  // 4096 B: PbT rows (absolute per-block offsets)
    __shared__ u32 bitsSh[CAPE / 32];        // 384 B: batch-wide event bits (desc-relative)
    __shared__ u32 wpart[8];
    __shared__ int cumLoc[GBIN + 1];

    int t0 = blockIdx.x * GBIN;
    int G2 = min(GBIN, KSEG - t0);
    if (G2 <= 0) return;
    int tid = threadIdx.x;
    int lane = tid & 63, wid = tid >> 6;

    for (int i = tid; i < (G2 + 1) * NBLK; i += 512) {
        int t = i >> 9, b = i & (NBLK - 1);
        rows[i] = PbT[(size_t)(t0 + t) * NBLK + b];
    }
    if (tid <= G2) cumLoc[tid] = cum[t0 + tid];
    __syncthreads();

    int u = 0;
    while (u < G2) {
        int m = 1;
        while (u + m < G2 && cumLoc[u + m + 1] - cumLoc[u] <= CAPE) ++m;
        int aBatch = cumLoc[u];
        int tot = cumLoc[u + m] - aBatch;
        int descbase = N - cumLoc[u + m];

        // ---- run lengths (3/thread chains) + exclusive scan -> ofs (u16) ----
        int base3 = tid * 3;
        int r3[3];
        int sum3 = 0;
        for (int k = 0; k < 3; ++k) {
            int idx = base3 + k;
            int tt = idx >> 9, bb = idx & (NBLK - 1);
            int lk = (tt < m)
                   ? (int)rows[(u + tt + 1) * NBLK + bb] - (int)rows[(u + tt) * NBLK + bb]
                   : 0;
            r3[k] = sum3;
            sum3 += lk;
        }
        int v = sum3;
        for (int off = 1; off < 64; off <<= 1) {
            int x = __shfl_up(v, off);
            if (lane >= off) v += x;
        }
        if (lane == 63) wpart[wid] = (u32)v;
        __syncthreads();
        if (tid == 0) {
            u32 run = 0;
            for (int w = 0; w < 8; ++w) { u32 tmp = wpart[w]; wpart[w] = run; run += tmp; }
        }
        __syncthreads();
        {
            int excl3 = v - sum3 + (int)wpart[wid];
            for (int k = 0; k < 3; ++k) ofs[base3 + k] = (u16)(excl3 + r3[k]);
        }
        __syncthreads();

        // ---- phase A: pair-owner writes pid (tiny LDS writes) + zero event bits ----
        for (int i = tid; i < m * NBLK; i += 512) {
            int tt = i >> 9, bb = i & (NBLK - 1);
            int l = (int)rows[(u + tt + 1) * NBLK + bb] - (int)rows[(u + tt) * NBLK + bb];
            int o = (int)ofs[i];
            for (int k = 0; k < l; ++k) pid[o + k] = (u16)i;
        }
        {
            int nw = (tot + 31) >> 5;
            for (int k = tid; k < nw; k += 512) bitsSh[k] = 0;
        }
        __syncthreads();

        // ---- phase B: element-parallel gather (independent 8B loads, high MLP) ----
        for (int x = tid; x < tot; x += 512) {
            int p = (int)pid[x];
            int tt = p >> 9, bb = p & (NBLK - 1);
            int r0 = (int)rows[(u + tt) * NBLK + bb];
            int k = x - (int)ofs[p];
            sm[x] = S[(size_t)bb * chunk + r0 + k];
        }
        __syncthreads();

        // ---- phase C: pair-parallel insertion sort of LDS-resident runs ----
        for (int i = tid; i < m * NBLK; i += 512) {
            int tt = i >> 9, bb = i & (NBLK - 1);
            int l = (int)rows[(u + tt + 1) * NBLK + bb] - (int)rows[(u + tt) * NBLK + bb];
            int o = (int)ofs[i];
            for (int k = 1; k < l; ++k) {
                u64 key = sm[o + k];
                int jj = o + k - 1;
                while (jj >= o && sm[jj] > key) { sm[jj + 1] = sm[jj]; --jj; }
                sm[jj + 1] = key;
            }
        }
        __syncthreads();

        // ---- phase D: batch-wide emit (J coalesced; P run-coalesced; bits to LDS) ----
        for (int x = tid; x < tot; x += 512) {
            int lt = (int)pid[x] >> 9;                       // batch-local bin, no search
            u64 rec = sm[x];
            int i_in = x - (cumLoc[u + lt] - aBatch);
            int descpos = N - cumLoc[u + lt + 1] + i_in;
            P[descpos] = expf(__uint_as_float((u32)rec));
            J[aBatch + x] = (u32)(rec >> 33);
            if (rec & 0x100000000ull) {
                int bi = descpos - descbase;
                atomicOr(&bitsSh[bi >> 5], 1u << (bi & 31));
            }
        }
        // binhint for every 256-boundary inside this batch (global bin id)
        {
            int k0 = (aBatch + 255) >> 8;
            int k1e = cumLoc[u + m];
            for (int kk = k0 + tid; (kk << 8) < k1e; kk += 512) {
                int p = kk << 8;
                int lt = 0;
                while (p >= cumLoc[u + lt + 1]) ++lt;
                binhint[kk] = (u16)(t0 + u + lt);
            }
        }
        __syncthreads();

        // ---- flush event bits to global (edge words shared across blocks -> atomicOr) ----
        {
            int nw = (tot + 31) >> 5;
            for (int k = tid; k < nw; k += 512) {
                u32 vv = bitsSh[k];
                if (!vv) continue;
                long gb = (long)descbase + 32l * k;
                int w = (int)(gb >> 5), sh = (int)(gb & 31);
                atomicOr(&E2w[w], vv << sh);
                if (sh && (vv >> (32 - sh))) atomicOr(&E2w[w + 1], vv >> (32 - sh));
            }
        }
        __syncthreads();
        u += m;
    }
}

// ---------------- segment sums: LDS histogram then DIRECT global atomic flush ----------
// R6 lesson: the partials+reduce_sums pipeline cost 148 us at 1.6% occupancy (40 blocks x
// 512 serial strided loads). Non-zero-bin atomic flush: ~7.9K expg + ~5.4K evs atomics per
// block over 10000 addresses -> negligible contention, no partials traffic, no 2nd kernel.
// evs as float is exact (per-bin counts << 2^24).
__global__ __launch_bounds__(1024) void sums3(const int* __restrict__ dur,
                                              const float* __restrict__ P,
                                              const u32* __restrict__ E2w,
                                              float* __restrict__ expg,
                                              float* __restrict__ evs,
                                              int N, int chunk) {
    __shared__ float he[KSEG];
    __shared__ int hv[KSEG];
    for (int i = threadIdx.x; i < KSEG; i += blockDim.x) { he[i] = 0.f; hv[i] = 0; }
    __syncthreads();
    int b = blockIdx.x;
    int s = b * chunk, e = min(N, s + chunk);
    for (int j = s + threadIdx.x; j < e; j += blockDim.x) {
        int t = dur[j];
        atomicAdd(&he[t], P[j]);
        if ((E2w[j >> 5] >> (j & 31)) & 1u) atomicAdd(&hv[t], 1);
    }
    __syncthreads();
    for (int i = threadIdx.x; i < KSEG; i += blockDim.x) {
        float a = he[i];
        int v = hv[i];
        if (a != 0.f) atomicAdd(&expg[i], a);
        if (v) atomicAdd(&evs[i], (float)v);
    }
}

// ---------------- risk suffix-sum + baseline hazard + total events (wave-shuffle) --------
__global__ __launch_bounds__(1024) void baseline_kernel(const float* __restrict__ expg,
                                                        const float* __restrict__ evs,
                                                        float* __restrict__ base,
                                                        float* __restrict__ ev_total, int K) {
    __shared__ float fwsum[16];
    __shared__ float carry_s;
    int tid = threadIdx.x, lane = tid & 63, wid = tid >> 6;
    if (tid == 0) carry_s = 0.f;
    float evloc = 0.f;
    __syncthreads();
    for (int b = 0; b < K; b += 1024) {
        int u = b + tid;
        int t = K - 1 - u;
        float h = 0.f, ev = 0.f;
        if (u < K) { h = expg[t]; ev = evs[t]; }
        evloc += ev;
        float v = h;
        for (int off = 1; off < 64; off <<= 1) {
            float x = __shfl_up(v, off);
            if (lane >= off) v += x;
        }
        if (lane == 63) fwsum[wid] = v;
        __syncthreads();
        if (wid == 0) {
            float wv = (lane < 16) ? fwsum[lane] : 0.f;
            for (int off = 1; off < 16; off <<= 1) {
                float x = __shfl_up(wv, off);
                if (lane >= off) wv += x;
            }
            if (lane < 16) fwsum[lane] = wv;
        }
        __syncthreads();
        float risk = v + ((wid > 0) ? fwsum[wid - 1] : 0.f) + carry_s;  // inclusive suffix
        if (u < K) base[t] = (risk > 0.f) ? ev / risk : 0.f;
        __syncthreads();
        if (tid == 1023) carry_s = risk;
    }
    // total events: wave reduce + cross-wave
    for (int off = 32; off > 0; off >>= 1) evloc += __shfl_down(evloc, off);
    __syncthreads();
    if (lane == 0) fwsum[wid] = evloc;
    __syncthreads();
    if (tid == 0) {
        float st = 0.f;
        for (int w = 0; w < 16; ++w) st += fwsum[w];
        ev_total[0] = st;
    }
}

// ---------------- MSE, flat grid-stride: (base[t(i)]*P[i] - E2bit[J[i]])^2 ----------------
__global__ __launch_bounds__(1024) void mse4(const float* __restrict__ P,
                                             const u32* __restrict__ J,
                                             const u32* __restrict__ E2w,
                                             const int* __restrict__ cum,
                                             const u16* __restrict__ binhint,
                                             const float* __restrict__ base,
                                             double* __restrict__ acc, int N) {
    int stride = gridDim.x * blockDim.x;
    double s = 0.0;
    for (int i = blockIdx.x * blockDim.x + threadIdx.x; i < N; i += stride) {
        int t = (int)binhint[i >> 8];
        while (cum[t + 1] <= i) ++t;
        u32 x = J[i];
        float ev = (float)((E2w[x >> 5] >> (x & 31)) & 1u);
        float d = base[t] * P[i] - ev;
        s += (double)d * (double)d;
    }
    __shared__ double sm[1024];
    sm[threadIdx.x] = s;
    __syncthreads();
    for (int o = 512; o > 0; o >>= 1) {
        if ((int)threadIdx.x < o) sm[threadIdx.x] += sm[threadIdx.x + o];
        __syncthreads();
    }
    if (threadIdx.x == 0) atomicAdd(acc, sm[0]);
}

__global__ void final_kernel(const double* __restrict__ acc, const float* __restrict__ ev_total,
                             float* __restrict__ out, int N) {
    out[0] = (ev_total[0] == 0.f) ? 0.0f : (float)(*acc / (double)N);
}

extern "C" void kernel_launch(void* const* d_in, const int* in_sizes, int n_in,
                              void* d_out, int out_size, void* d_ws, size_t ws_size,
                              hipStream_t stream) {
    const float* log_h = (const float*)d_in[0];
    const int* dur     = (const int*)d_in[1];
    const int* events  = (const int*)d_in[2];
    int N = in_sizes[0];
    float* out = (float*)d_out;

    char* ws = (char*)d_ws;
    size_t off = 0;
    auto alloc = [&](size_t bytes) -> char* {
        char* p = ws + off;
        off = (off + bytes + 255) & ~(size_t)255;
        return p;
    };
    // zeroed region: acc + E2w + expg + evs (atomic-accumulated buffers)
    double* acc  = (double*)alloc(8);
    u32*    E2w  = (u32*)alloc(((size_t)N / 32 + 2) * 4);   // event bitfield (desc-indexed)
    float*  expg = (float*)alloc(KSEG * 4);
    float*  evs  = (float*)alloc(KSEG * 4);
    size_t zero_bytes = off;
    float*  ev_total = (float*)alloc(4);
    int*    cum      = (int*)alloc((KSEG + 1) * 4);
    float*  base     = (float*)alloc(KSEG * 4);
    u16*    binhint  = (u16*)alloc(((size_t)N / 256 + 1) * 2);
    u16*    Pb       = (u16*)alloc((size_t)NBLK * (KSEG + 1) * 2);
    u16*    PbT      = (u16*)alloc((size_t)(KSEG + 1) * NBLK * 2);
    u64*    S        = (u64*)alloc((size_t)N * 8);
    float*  P        = (float*)alloc((size_t)N * 4);
    u32*    J        = (u32*)alloc((size_t)N * 4);
    (void)ws_size;

    int chunk = (N + NBLK - 1) / NBLK;   // 15625 <= CHUNKMAX -> u16 records valid

    hipMemsetAsync(d_ws, 0, zero_bytes, stream);

    localsort_lds<<<NBLK, 1024, 0, stream>>>(dur, log_h, events, S, Pb, N, chunk);
    transpose_pb<<<dim3((KSEG + 64) / 64, NBLK / 64), dim3(64, 4), 0, stream>>>(Pb, PbT);
    cum_rows<<<(KSEG + 4) / 4, 256, 0, stream>>>(PbT, cum);
    runsort_ep<<<(KSEG + GBIN - 1) / GBIN, 512, 0, stream>>>(S, cum, PbT, P, J, E2w,
                                                             binhint, N, chunk);
    sums3<<<NBLK, 1024, 0, stream>>>(dur, P, E2w, expg, evs, N, chunk);
    baseline_kernel<<<1, 1024, 0, stream>>>(expg, evs, base, ev_total, KSEG);
    mse4<<<512, 1024, 0, stream>>>(P, J, E2w, cum, binhint, base, acc, N);
    final_kernel<<<1, 1, 0, stream>>>(acc, ev_total, out, N);
}

// Round 8
// 377.817 us; speedup vs baseline: 1.3506x; 1.0582x over previous
//
#include <hip/hip_runtime.h>

#define KSEG 10000
#define NBLK 512          // sort blocks; chunk = 15625 <= 16384 -> u16 records, 2 blocks/CU
#define CHUNKMAX 16384    // rec16 capacity (15 bits local_j headroom: 14 bits used + ev)
#define GBIN 3            // bins per runsort block (~39 KB LDS -> 4 blocks/CU)
#define CAPE 3072         // runsort staging capacity (3-bin mean 2400, +13 sigma)
#define NXCD 8

typedef unsigned long long u64;
typedef unsigned int u32;
typedef unsigned short u16;
typedef unsigned char u8;

// ---------------- fused: hist + per-block scan + one-phase u16 LDS counting scatter ------
__global__ __launch_bounds__(1024) void localsort_lds(const int* __restrict__ dur,
                                                      const float* __restrict__ log_h,
                                                      const int* __restrict__ events,
                                                      u64* __restrict__ S,
                                                      u16* __restrict__ Pb,
                                                      int N, int chunk) {
    __shared__ u32 poolA[KSEG];          // 40000 B: h32 (pass1/scan), rec16 (scatter/dump)
    __shared__ u32 cp[KSEG / 2];         // 20000 B packed dual-u16 cursors
    __shared__ u32 wsum[16];
    __shared__ u32 carry_s;
    u32* h32 = poolA;
    u16* rec16 = (u16*)poolA;            // 32768 B < 40000 B, h32 dead before first write

    int b = blockIdx.x;
    int s = b * chunk, e = min(N, s + chunk);
    int tid = threadIdx.x;
    int lane = tid & 63, wid = tid >> 6;
    int kiter = (chunk + 1023) >> 10;    // 16 for N=8M (<=32 so myev bitmask fits u32)

    for (int i = tid; i < KSEG; i += 1024) h32[i] = 0;
    if (tid == 0) carry_s = 0;
    __syncthreads();

    // ---- pass 1: histogram; events -> register bitmask ----
    u32 myev = 0;
    for (int k = 0; k < kiter; ++k) {
        int j = s + tid + (k << 10);
        if (j < e) {
            int d = dur[j];
            myev |= (u32)(events[j] & 1) << k;
            atomicAdd(&h32[d], 1);
        }
    }
    __syncthreads();

    // ---- exclusive scan over KSEG bins (strips of 1024, wave-shuffle scan) ----
    for (int base = 0; base < KSEG; base += 1024) {
        int t = base + tid;
        u32 h = (t < KSEG) ? h32[t] : 0;
        u32 v = h;
        for (int off = 1; off < 64; off <<= 1) {
            u32 x = __shfl_up(v, off);
            if (lane >= off) v += x;
        }
        if (lane == 63) wsum[wid] = v;
        __syncthreads();
        if (wid == 0) {
            u32 wv = (lane < 16) ? wsum[lane] : 0;
            for (int off = 1; off < 16; off <<= 1) {
                u32 x = __shfl_up(wv, off);
                if (lane >= off) wv += x;
            }
            if (lane < 16) wsum[lane] = wv;
        }
        __syncthreads();
        u32 incl = v + ((wid > 0) ? wsum[wid - 1] : 0) + carry_s;
        u32 excl = incl - h;
        if (t < KSEG) {
            Pb[(size_t)b * (KSEG + 1) + t] = (u16)excl;
            if (!(t & 1)) cp[t >> 1] = excl | (incl << 16);  // excl_t | excl_{t+1}<<16
        }
        __syncthreads();
        if (tid == 1023) carry_s = incl;
    }
    __syncthreads();
    u32 total = carry_s;
    if (tid == 0) Pb[(size_t)b * (KSEG + 1) + KSEG] = (u16)total;
    __syncthreads();

    // ---- single scatter phase: u16 records (dur re-read, L2-warm) ----
    for (int k = 0; k < kiter; ++k) {
        int j = s + tid + (k << 10);
        if (j < e) {
            int d = dur[j];
            u32 add = (d & 1) ? 0x10000u : 1u;
            u32 old = atomicAdd(&cp[d >> 1], add);
            u32 pos = (d & 1) ? (old >> 16) : (old & 0xffffu);
            rec16[pos] = (u16)((u32)((tid + (k << 10)) << 1) | ((myev >> k) & 1u));
        }
    }
    __syncthreads();

    // ---- coalesced dump: reconstruct u64 records; log_h gather in 62.5 KB window ----
    for (u32 i = tid; i < total; i += 1024) {
        u32 v = rec16[i];
        int j = s + (int)(v >> 1);
        u32 hi = ((u32)j << 1) | (v & 1u);
        S[(size_t)s + i] = ((u64)hi << 32) | (u64)__float_as_uint(log_h[j]);
    }
}

// ---------------- transpose Pb[NBLK][K+1] -> PbT[K+1][NBLK] ----------------
__global__ void transpose_pb(const u16* __restrict__ Pb, u16* __restrict__ PbT) {
    __shared__ u16 tile[64][65];
    int t0 = blockIdx.x * 64;
    int b0 = blockIdx.y * 64;
    int tx = threadIdx.x;        // 0..63
    int ty = threadIdx.y;        // 0..3
    for (int r = ty; r < 64; r += 4) {
        int b = b0 + r, t = t0 + tx;
        tile[r][tx] = (b < NBLK && t <= KSEG) ? Pb[(size_t)b * (KSEG + 1) + t] : (u16)0;
    }
    __syncthreads();
    for (int r = ty; r < 64; r += 4) {
        int t = t0 + r, b = b0 + tx;
        if (t <= KSEG && b < NBLK) PbT[(size_t)t * NBLK + b] = tile[tx][r];
    }
}

// ---------------- cum[t] = sum_b Pb[b][t] ----------------
__global__ __launch_bounds__(256) void cum_rows(const u16* __restrict__ PbT,
                                                int* __restrict__ cum) {
    int r = blockIdx.x * 4 + (threadIdx.x >> 6);
    if (r > KSEG) return;
    int lane = threadIdx.x & 63;
    const uint4* row = (const uint4*)(PbT + (size_t)r * NBLK);  // 64 uint4 = 512 u16
    uint4 v = row[lane];
    int sum = (int)(v.x & 0xffff) + (int)(v.x >> 16) + (int)(v.y & 0xffff) + (int)(v.y >> 16)
            + (int)(v.z & 0xffff) + (int)(v.z >> 16) + (int)(v.w & 0xffff) + (int)(v.w >> 16);
    for (int off = 32; off > 0; off >>= 1) sum += __shfl_down(sum, off);
    if (lane == 0) cum[r] = sum;
}

// ---------------- element-parallel runsort, XCD-swizzled + src-major coalesced gather ----
// R7 counters: FETCH 182 MB vs 77 ideal (128B line per ~37B batch range, duplicated
// across XCD L2s by round-robin dispatch). Fix 1: bijective XCD swizzle -> consecutive
// bin-ranges share an XCD L2. Fix 2: gather ordered by (src block, row): consecutive
// lanes read consecutive addresses -> wave coalescing merges a range into 1-2 txns.
__global__ __launch_bounds__(512, 8) void runsort_ep(const u64* __restrict__ S,
                                                     const int* __restrict__ cum,
                                                     const u16* __restrict__ PbT,
                                                     float* __restrict__ P,
                                                     u32* __restrict__ J,
                                                     u32* __restrict__ E2w,
                                                     u16* __restrict__ binhint,
                                                     int N, int chunk) {
    __shared__ u64 sm[CAPE];                 // 24576 B staging (indexed by asc pos x)
    __shared__ u16 pidy[CAPE];               // 6144 B: gather idx y -> src block bb
    __shared__ u16 ofs[GBIN * NBLK];         // 3072 B: x-space run offsets (tt*NBLK+bb)
    __shared__ u16 rofs[NBLK];               // 1024 B: y-space src-block offsets
    __shared__ u16 rows[(GBIN + 1) * NBLK];  // 4096 B: PbT rows (block-local S offsets)
    __shared__ u32 bitsSh[CAPE / 32];        // 384 B: batch-wide event bits (desc-relative)
    __shared__ u32 wpart[8];
    __shared__ int cumLoc[GBIN + 1];

    // bijective XCD swizzle (nwg = 3334, nwg%8 != 0 -> m204 variant)
    int nwg = (KSEG + GBIN - 1) / GBIN;
    int q = nwg / NXCD, r8 = nwg % NXCD;
    int xcd = blockIdx.x % NXCD, sub = blockIdx.x / NXCD;
    int wg = (xcd < r8 ? xcd * (q + 1) : r8 * (q + 1) + (xcd - r8) * q) + sub;

    int t0 = wg * GBIN;
    int G2 = min(GBIN, KSEG - t0);
    if (G2 <= 0) return;
    int tid = threadIdx.x;
    int lane = tid & 63, wid = tid >> 6;

    for (int i = tid; i < (G2 + 1) * NBLK; i += 512) {
        int t = i >> 9, b = i & (NBLK - 1);
        rows[i] = PbT[(size_t)(t0 + t) * NBLK + b];
    }
    if (tid <= G2) cumLoc[tid] = cum[t0 + tid];
    __syncthreads();

    int u = 0;
    while (u < G2) {
        int m = 1;
        while (u + m < G2 && cumLoc[u + m + 1] - cumLoc[u] <= CAPE) ++m;
        int aBatch = cumLoc[u];
        int tot = cumLoc[u + m] - aBatch;
        int descbase = N - cumLoc[u + m];

        // ---- x-space offsets: run lengths (3/thread chains) + excl scan -> ofs ----
        int base3 = tid * 3;
        int r3[3];
        int sum3 = 0;
        for (int k = 0; k < 3; ++k) {
            int idx = base3 + k;
            int tt = idx >> 9, bb = idx & (NBLK - 1);
            int lk = (tt < m)
                   ? (int)rows[(u + tt + 1) * NBLK + bb] - (int)rows[(u + tt) * NBLK + bb]
                   : 0;
            r3[k] = sum3;
            sum3 += lk;
        }
        int v = sum3;
        for (int off = 1; off < 64; off <<= 1) {
            int x = __shfl_up(v, off);
            if (lane >= off) v += x;
        }
        if (lane == 63) wpart[wid] = (u32)v;
        __syncthreads();
        if (tid == 0) {
            u32 run = 0;
            for (int w = 0; w < 8; ++w) { u32 tmp = wpart[w]; wpart[w] = run; run += tmp; }
        }
        __syncthreads();
        {
            int excl3 = v - sum3 + (int)wpart[wid];
            for (int k = 0; k < 3; ++k) ofs[base3 + k] = (u16)(excl3 + r3[k]);
        }
        __syncthreads();

        // ---- y-space offsets: per-src-block batch range lengths + excl scan -> rofs ----
        int bb = tid;   // 512 threads == NBLK
        int rl = (int)rows[(u + m) * NBLK + bb] - (int)rows[u * NBLK + bb];
        int vy = rl;
        for (int off = 1; off < 64; off <<= 1) {
            int x = __shfl_up(vy, off);
            if (lane >= off) vy += x;
        }
        if (lane == 63) wpart[wid] = (u32)vy;
        __syncthreads();
        if (tid == 0) {
            u32 run = 0;
            for (int w = 0; w < 8; ++w) { u32 tmp = wpart[w]; wpart[w] = run; run += tmp; }
        }
        __syncthreads();
        {
            int excl = vy - rl + (int)wpart[wid];
            rofs[bb] = (u16)excl;
            for (int k = 0; k < rl; ++k) pidy[excl + k] = (u16)bb;  // own range, no sync
        }
        {
            int nw = (tot + 31) >> 5;
            for (int k = tid; k < nw; k += 512) bitsSh[k] = 0;
        }
        __syncthreads();

        // ---- gather, src-major order: consecutive y = consecutive addresses ----
        for (int y = tid; y < tot; y += 512) {
            int b2 = (int)pidy[y];
            int r0 = (int)rows[u * NBLK + b2];
            int r = r0 + (y - (int)rofs[b2]);
            u64 val = S[(size_t)b2 * chunk + r];
            int lt = 0;
            while (lt + 1 < m && r >= (int)rows[(u + lt + 1) * NBLK + b2]) ++lt;
            int x = (int)ofs[lt * NBLK + b2] + (r - (int)rows[(u + lt) * NBLK + b2]);
            sm[x] = val;
        }
        __syncthreads();

        // ---- pair-parallel insertion sort of LDS-resident runs ----
        for (int i = tid; i < m * NBLK; i += 512) {
            int tt = i >> 9, b2 = i & (NBLK - 1);
            int l = (int)rows[(u + tt + 1) * NBLK + b2] - (int)rows[(u + tt) * NBLK + b2];
            int o = (int)ofs[i];
            for (int k = 1; k < l; ++k) {
                u64 key = sm[o + k];
                int jj = o + k - 1;
                while (jj >= o && sm[jj] > key) { sm[jj + 1] = sm[jj]; --jj; }
                sm[jj + 1] = key;
            }
        }
        __syncthreads();

        // ---- batch-wide emit (lt from cumLoc compares; J coalesced; bits to LDS) ----
        for (int x = tid; x < tot; x += 512) {
            int lt = 0;
            while (lt + 1 < m && x >= cumLoc[u + lt + 1] - aBatch) ++lt;
            u64 rec = sm[x];
            int i_in = x - (cumLoc[u + lt] - aBatch);
            int descpos = N - cumLoc[u + lt + 1] + i_in;
            P[descpos] = expf(__uint_as_float((u32)rec));
            J[aBatch + x] = (u32)(rec >> 33);
            if (rec & 0x100000000ull) {
                int bi = descpos - descbase;
                atomicOr(&bitsSh[bi >> 5], 1u << (bi & 31));
            }
        }
        // binhint for every 256-boundary inside this batch (global bin id)
        {
            int k0 = (aBatch + 255) >> 8;
            int k1e = cumLoc[u + m];
            for (int kk = k0 + tid; (kk << 8) < k1e; kk += 512) {
                int p = kk << 8;
                int lt = 0;
                while (p >= cumLoc[u + lt + 1]) ++lt;
                binhint[kk] = (u16)(t0 + u + lt);
            }
        }
        __syncthreads();

        // ---- flush event bits to global (edge words shared across blocks -> atomicOr) ----
        {
            int nw = (tot + 31) >> 5;
            for (int k = tid; k < nw; k += 512) {
                u32 vv = bitsSh[k];
                if (!vv) continue;
                long gb = (long)descbase + 32l * k;
                int w = (int)(gb >> 5), sh = (int)(gb & 31);
                atomicOr(&E2w[w], vv << sh);
                if (sh && (vv >> (32 - sh))) atomicOr(&E2w[w + 1], vv >> (32 - sh));
            }
        }
        __syncthreads();
        u += m;
    }
}

// ---------------- segment sums: LDS histogram then DIRECT global atomic flush ----------
__global__ __launch_bounds__(1024) void sums3(const int* __restrict__ dur,
                                              const float* __restrict__ P,
                                              const u32* __restrict__ E2w,
                                              float* __restrict__ expg,
                                              float* __restrict__ evs,
                                              int N, int chunk) {
    __shared__ float he[KSEG];
    __shared__ int hv[KSEG];
    for (int i = threadIdx.x; i < KSEG; i += blockDim.x) { he[i] = 0.f; hv[i] = 0; }
    __syncthreads();
    int b = blockIdx.x;
    int s = b * chunk, e = min(N, s + chunk);
    for (int j = s + threadIdx.x; j < e; j += blockDim.x) {
        int t = dur[j];
        atomicAdd(&he[t], P[j]);
        if ((E2w[j >> 5] >> (j & 31)) & 1u) atomicAdd(&hv[t], 1);
    }
    __syncthreads();
    for (int i = threadIdx.x; i < KSEG; i += blockDim.x) {
        float a = he[i];
        int v = hv[i];
        if (a != 0.f) atomicAdd(&expg[i], a);
        if (v) atomicAdd(&evs[i], (float)v);
    }
}

// ---------------- risk suffix-sum + baseline hazard + total events (wave-shuffle) --------
__global__ __launch_bounds__(1024) void baseline_kernel(const float* __restrict__ expg,
                                                        const float* __restrict__ evs,
                                                        float* __restrict__ base,
                                                        float* __restrict__ ev_total, int K) {
    __shared__ float fwsum[16];
    __shared__ float carry_s;
    int tid = threadIdx.x, lane = tid & 63, wid = tid >> 6;
    if (tid == 0) carry_s = 0.f;
    float evloc = 0.f;
    __syncthreads();
    for (int b = 0; b < K; b += 1024) {
        int u = b + tid;
        int t = K - 1 - u;
        float h = 0.f, ev = 0.f;
        if (u < K) { h = expg[t]; ev = evs[t]; }
        evloc += ev;
        float v = h;
        for (int off = 1; off < 64; off <<= 1) {
            float x = __shfl_up(v, off);
            if (lane >= off) v += x;
        }
        if (lane == 63) fwsum[wid] = v;
        __syncthreads();
        if (wid == 0) {
            float wv = (lane < 16) ? fwsum[lane] : 0.f;
            for (int off = 1; off < 16; off <<= 1) {
                float x = __shfl_up(wv, off);
                if (lane >= off) wv += x;
            }
            if (lane < 16) fwsum[lane] = wv;
        }
        __syncthreads();
        float risk = v + ((wid > 0) ? fwsum[wid - 1] : 0.f) + carry_s;  // inclusive suffix
        if (u < K) base[t] = (risk > 0.f) ? ev / risk : 0.f;
        __syncthreads();
        if (tid == 1023) carry_s = risk;
    }
    // total events: wave reduce + cross-wave
    for (int off = 32; off > 0; off >>= 1) evloc += __shfl_down(evloc, off);
    __syncthreads();
    if (lane == 0) fwsum[wid] = evloc;
    __syncthreads();
    if (tid == 0) {
        float st = 0.f;
        for (int w = 0; w < 16; ++w) st += fwsum[w];
        ev_total[0] = st;
    }
}

// ---------------- MSE, flat grid-stride: (base[t(i)]*P[i] - E2bit[J[i]])^2 ----------------
__global__ __launch_bounds__(1024) void mse4(const float* __restrict__ P,
                                             const u32* __restrict__ J,
                                             const u32* __restrict__ E2w,
                                             const int* __restrict__ cum,
                                             const u16* __restrict__ binhint,
                                             const float* __restrict__ base,
                                             double* __restrict__ acc, int N) {
    int stride = gridDim.x * blockDim.x;
    double s = 0.0;
    for (int i = blockIdx.x * blockDim.x + threadIdx.x; i < N; i += stride) {
        int t = (int)binhint[i >> 8];
        while (cum[t + 1] <= i) ++t;
        u32 x = J[i];
        float ev = (float)((E2w[x >> 5] >> (x & 31)) & 1u);
        float d = base[t] * P[i] - ev;
        s += (double)d * (double)d;
    }
    __shared__ double sm[1024];
    sm[threadIdx.x] = s;
    __syncthreads();
    for (int o = 512; o > 0; o >>= 1) {
        if ((int)threadIdx.x < o) sm[threadIdx.x] += sm[threadIdx.x + o];
        __syncthreads();
    }
    if (threadIdx.x == 0) atomicAdd(acc, sm[0]);
}

__global__ void final_kernel(const double* __restrict__ acc, const float* __restrict__ ev_total,
                             float* __restrict__ out, int N) {
    out[0] = (ev_total[0] == 0.f) ? 0.0f : (float)(*acc / (double)N);
}

extern "C" void kernel_launch(void* const* d_in, const int* in_sizes, int n_in,
                              void* d_out, int out_size, void* d_ws, size_t ws_size,
                              hipStream_t stream) {
    const float* log_h = (const float*)d_in[0];
    const int* dur     = (const int*)d_in[1];
    const int* events  = (const int*)d_in[2];
    int N = in_sizes[0];
    float* out = (float*)d_out;

    char* ws = (char*)d_ws;
    size_t off = 0;
    auto alloc = [&](size_t bytes) -> char* {
        char* p = ws + off;
        off = (off + bytes + 255) & ~(size_t)255;
        return p;
    };
    // zeroed region: acc + E2w + expg + evs (atomic-accumulated buffers)
    double* acc  = (double*)alloc(8);
    u32*    E2w  = (u32*)alloc(((size_t)N / 32 + 2) * 4);   // event bitfield (desc-indexed)
    float*  expg = (float*)alloc(KSEG * 4);
    float*  evs  = (float*)alloc(KSEG * 4);
    size_t zero_bytes = off;
    float*  ev_total = (float*)alloc(4);
    int*    cum      = (int*)alloc((KSEG + 1) * 4);
    float*  base     = (float*)alloc(KSEG * 4);
    u16*    binhint  = (u16*)alloc(((size_t)N / 256 + 1) * 2);
    u16*    Pb       = (u16*)alloc((size_t)NBLK * (KSEG + 1) * 2);
    u16*    PbT      = (u16*)alloc((size_t)(KSEG + 1) * NBLK * 2);
    u64*    S        = (u64*)alloc((size_t)N * 8);
    float*  P        = (float*)alloc((size_t)N * 4);
    u32*    J        = (u32*)alloc((size_t)N * 4);
    (void)ws_size;

    int chunk = (N + NBLK - 1) / NBLK;   // 15625 <= CHUNKMAX -> u16 records valid

    hipMemsetAsync(d_ws, 0, zero_bytes, stream);

    localsort_lds<<<NBLK, 1024, 0, stream>>>(dur, log_h, events, S, Pb, N, chunk);
    transpose_pb<<<dim3((KSEG + 64) / 64, NBLK / 64), dim3(64, 4), 0, stream>>>(Pb, PbT);
    cum_rows<<<(KSEG + 4) / 4, 256, 0, stream>>>(PbT, cum);
    runsort_ep<<<(KSEG + GBIN - 1) / GBIN, 512, 0, stream>>>(S, cum, PbT, P, J, E2w,
                                                             binhint, N, chunk);
    sums3<<<NBLK, 1024, 0, stream>>>(dur, P, E2w, expg, evs, N, chunk);
    baseline_kernel<<<1, 1024, 0, stream>>>(expg, evs, base, ev_total, KSEG);
    mse4<<<512, 1024, 0, stream>>>(P, J, E2w, cum, binhint, base, acc, N);
    final_kernel<<<1, 1, 0, stream>>>(acc, ev_total, out, N);
}

// Round 9
// 349.190 us; speedup vs baseline: 1.4613x; 1.0820x over previous
//
#include <hip/hip_runtime.h>

#define KSEG 10000
#define NBLK 512          // sort blocks; chunk = 15625 <= 16384 -> u16 records, 2 blocks/CU
#define CHUNKMAX 16384    // rec16 capacity (15 bits local_j headroom: 14 bits used + ev)
#define GBIN 3            // bins per runsort block (~39 KB LDS -> 4 blocks/CU)
#define CAPE 3072         // runsort staging capacity (3-bin mean 2400, +13 sigma)
#define NXCD 8
#define RB 64             // reduce_part: b-rows per block

typedef unsigned long long u64;
typedef unsigned int u32;
typedef unsigned short u16;
typedef unsigned char u8;

// ---------------- fused: hist + per-block scan + one-phase u16 LDS counting scatter ------
__global__ __launch_bounds__(1024) void localsort_lds(const int* __restrict__ dur,
                                                      const float* __restrict__ log_h,
                                                      const int* __restrict__ events,
                                                      u64* __restrict__ S,
                                                      u16* __restrict__ Pb,
                                                      int N, int chunk) {
    __shared__ u32 poolA[KSEG];          // 40000 B: h32 (pass1/scan), rec16 (scatter/dump)
    __shared__ u32 cp[KSEG / 2];         // 20000 B packed dual-u16 cursors
    __shared__ u32 wsum[16];
    __shared__ u32 carry_s;
    u32* h32 = poolA;
    u16* rec16 = (u16*)poolA;            // 32768 B < 40000 B, h32 dead before first write

    int b = blockIdx.x;
    int s = b * chunk, e = min(N, s + chunk);
    int tid = threadIdx.x;
    int lane = tid & 63, wid = tid >> 6;
    int kiter = (chunk + 1023) >> 10;    // 16 for N=8M (<=32 so myev bitmask fits u32)

    for (int i = tid; i < KSEG; i += 1024) h32[i] = 0;
    if (tid == 0) carry_s = 0;
    __syncthreads();

    // ---- pass 1: histogram; events -> register bitmask ----
    u32 myev = 0;
    for (int k = 0; k < kiter; ++k) {
        int j = s + tid + (k << 10);
        if (j < e) {
            int d = dur[j];
            myev |= (u32)(events[j] & 1) << k;
            atomicAdd(&h32[d], 1);
        }
    }
    __syncthreads();

    // ---- exclusive scan over KSEG bins (strips of 1024, wave-shuffle scan) ----
    for (int base = 0; base < KSEG; base += 1024) {
        int t = base + tid;
        u32 h = (t < KSEG) ? h32[t] : 0;
        u32 v = h;
        for (int off = 1; off < 64; off <<= 1) {
            u32 x = __shfl_up(v, off);
            if (lane >= off) v += x;
        }
        if (lane == 63) wsum[wid] = v;
        __syncthreads();
        if (wid == 0) {
            u32 wv = (lane < 16) ? wsum[lane] : 0;
            for (int off = 1; off < 16; off <<= 1) {
                u32 x = __shfl_up(wv, off);
                if (lane >= off) wv += x;
            }
            if (lane < 16) wsum[lane] = wv;
        }
        __syncthreads();
        u32 incl = v + ((wid > 0) ? wsum[wid - 1] : 0) + carry_s;
        u32 excl = incl - h;
        if (t < KSEG) {
            Pb[(size_t)b * (KSEG + 1) + t] = (u16)excl;
            if (!(t & 1)) cp[t >> 1] = excl | (incl << 16);  // excl_t | excl_{t+1}<<16
        }
        __syncthreads();
        if (tid == 1023) carry_s = incl;
    }
    __syncthreads();
    u32 total = carry_s;
    if (tid == 0) Pb[(size_t)b * (KSEG + 1) + KSEG] = (u16)total;
    __syncthreads();

    // ---- single scatter phase: u16 records (dur re-read, L2-warm) ----
    for (int k = 0; k < kiter; ++k) {
        int j = s + tid + (k << 10);
        if (j < e) {
            int d = dur[j];
            u32 add = (d & 1) ? 0x10000u : 1u;
            u32 old = atomicAdd(&cp[d >> 1], add);
            u32 pos = (d & 1) ? (old >> 16) : (old & 0xffffu);
            rec16[pos] = (u16)((u32)((tid + (k << 10)) << 1) | ((myev >> k) & 1u));
        }
    }
    __syncthreads();

    // ---- coalesced dump: reconstruct u64 records; log_h gather in 62.5 KB window ----
    for (u32 i = tid; i < total; i += 1024) {
        u32 v = rec16[i];
        int j = s + (int)(v >> 1);
        u32 hi = ((u32)j << 1) | (v & 1u);
        S[(size_t)s + i] = ((u64)hi << 32) | (u64)__float_as_uint(log_h[j]);
    }
}

// ---------------- transpose Pb[NBLK][K+1] -> PbT[K+1][NBLK] ----------------
__global__ void transpose_pb(const u16* __restrict__ Pb, u16* __restrict__ PbT) {
    __shared__ u16 tile[64][65];
    int t0 = blockIdx.x * 64;
    int b0 = blockIdx.y * 64;
    int tx = threadIdx.x;        // 0..63
    int ty = threadIdx.y;        // 0..3
    for (int r = ty; r < 64; r += 4) {
        int b = b0 + r, t = t0 + tx;
        tile[r][tx] = (b < NBLK && t <= KSEG) ? Pb[(size_t)b * (KSEG + 1) + t] : (u16)0;
    }
    __syncthreads();
    for (int r = ty; r < 64; r += 4) {
        int t = t0 + r, b = b0 + tx;
        if (t <= KSEG && b < NBLK) PbT[(size_t)t * NBLK + b] = tile[tx][r];
    }
}

// ---------------- cum[t] = sum_b Pb[b][t] ----------------
__global__ __launch_bounds__(256) void cum_rows(const u16* __restrict__ PbT,
                                                int* __restrict__ cum) {
    int r = blockIdx.x * 4 + (threadIdx.x >> 6);
    if (r > KSEG) return;
    int lane = threadIdx.x & 63;
    const uint4* row = (const uint4*)(PbT + (size_t)r * NBLK);  // 64 uint4 = 512 u16
    uint4 v = row[lane];
    int sum = (int)(v.x & 0xffff) + (int)(v.x >> 16) + (int)(v.y & 0xffff) + (int)(v.y >> 16)
            + (int)(v.z & 0xffff) + (int)(v.z >> 16) + (int)(v.w & 0xffff) + (int)(v.w >> 16);
    for (int off = 32; off > 0; off >>= 1) sum += __shfl_down(sum, off);
    if (lane == 0) cum[r] = sum;
}

// ---------------- element-parallel runsort, XCD-swizzled + src-major coalesced gather ----
__global__ __launch_bounds__(512, 8) void runsort_ep(const u64* __restrict__ S,
                                                     const int* __restrict__ cum,
                                                     const u16* __restrict__ PbT,
                                                     float* __restrict__ P,
                                                     u32* __restrict__ J,
                                                     u32* __restrict__ E2w,
                                                     u16* __restrict__ binhint,
                                                     int N, int chunk) {
    __shared__ u64 sm[CAPE];                 // 24576 B staging (indexed by asc pos x)
    __shared__ u16 pidy[CAPE];               // 6144 B: gather idx y -> src block bb
    __shared__ u16 ofs[GBIN * NBLK];         // 3072 B: x-space run offsets (tt*NBLK+bb)
    __shared__ u16 rofs[NBLK];               // 1024 B: y-space src-block offsets
    __shared__ u16 rows[(GBIN + 1) * NBLK];  // 4096 B: PbT rows (block-local S offsets)
    __shared__ u32 bitsSh[CAPE / 32];        // 384 B: batch-wide event bits (desc-relative)
    __shared__ u32 wpart[8];
    __shared__ int cumLoc[GBIN + 1];

    // bijective XCD swizzle (nwg = 3334, nwg%8 != 0 -> m204 variant)
    int nwg = (KSEG + GBIN - 1) / GBIN;
    int q = nwg / NXCD, r8 = nwg % NXCD;
    int xcd = blockIdx.x % NXCD, sub = blockIdx.x / NXCD;
    int wg = (xcd < r8 ? xcd * (q + 1) : r8 * (q + 1) + (xcd - r8) * q) + sub;

    int t0 = wg * GBIN;
    int G2 = min(GBIN, KSEG - t0);
    if (G2 <= 0) return;
    int tid = threadIdx.x;
    int lane = tid & 63, wid = tid >> 6;

    for (int i = tid; i < (G2 + 1) * NBLK; i += 512) {
        int t = i >> 9, b = i & (NBLK - 1);
        rows[i] = PbT[(size_t)(t0 + t) * NBLK + b];
    }
    if (tid <= G2) cumLoc[tid] = cum[t0 + tid];
    __syncthreads();

    int u = 0;
    while (u < G2) {
        int m = 1;
        while (u + m < G2 && cumLoc[u + m + 1] - cumLoc[u] <= CAPE) ++m;
        int aBatch = cumLoc[u];
        int tot = cumLoc[u + m] - aBatch;
        int descbase = N - cumLoc[u + m];

        // ---- x-space offsets: run lengths (3/thread chains) + excl scan -> ofs ----
        int base3 = tid * 3;
        int r3[3];
        int sum3 = 0;
        for (int k = 0; k < 3; ++k) {
            int idx = base3 + k;
            int tt = idx >> 9, bb = idx & (NBLK - 1);
            int lk = (tt < m)
                   ? (int)rows[(u + tt + 1) * NBLK + bb] - (int)rows[(u + tt) * NBLK + bb]
                   : 0;
            r3[k] = sum3;
            sum3 += lk;
        }
        int v = sum3;
        for (int off = 1; off < 64; off <<= 1) {
            int x = __shfl_up(v, off);
            if (lane >= off) v += x;
        }
        if (lane == 63) wpart[wid] = (u32)v;
        __syncthreads();
        if (tid == 0) {
            u32 run = 0;
            for (int w = 0; w < 8; ++w) { u32 tmp = wpart[w]; wpart[w] = run; run += tmp; }
        }
        __syncthreads();
        {
            int excl3 = v - sum3 + (int)wpart[wid];
            for (int k = 0; k < 3; ++k) ofs[base3 + k] = (u16)(excl3 + r3[k]);
        }
        __syncthreads();

        // ---- y-space offsets: per-src-block batch range lengths + excl scan -> rofs ----
        int bb = tid;   // 512 threads == NBLK
        int rl = (int)rows[(u + m) * NBLK + bb] - (int)rows[u * NBLK + bb];
        int vy = rl;
        for (int off = 1; off < 64; off <<= 1) {
            int x = __shfl_up(vy, off);
            if (lane >= off) vy += x;
        }
        if (lane == 63) wpart[wid] = (u32)vy;
        __syncthreads();
        if (tid == 0) {
            u32 run = 0;
            for (int w = 0; w < 8; ++w) { u32 tmp = wpart[w]; wpart[w] = run; run += tmp; }
        }
        __syncthreads();
        {
            int excl = vy - rl + (int)wpart[wid];
            rofs[bb] = (u16)excl;
            for (int k = 0; k < rl; ++k) pidy[excl + k] = (u16)bb;  // own range, no sync
        }
        {
            int nw = (tot + 31) >> 5;
            for (int k = tid; k < nw; k += 512) bitsSh[k] = 0;
        }
        __syncthreads();

        // ---- gather, src-major order: consecutive y = consecutive addresses ----
        for (int y = tid; y < tot; y += 512) {
            int b2 = (int)pidy[y];
            int r0 = (int)rows[u * NBLK + b2];
            int r = r0 + (y - (int)rofs[b2]);
            u64 val = S[(size_t)b2 * chunk + r];
            int lt = 0;
            while (lt + 1 < m && r >= (int)rows[(u + lt + 1) * NBLK + b2]) ++lt;
            int x = (int)ofs[lt * NBLK + b2] + (r - (int)rows[(u + lt) * NBLK + b2]);
            sm[x] = val;
        }
        __syncthreads();

        // ---- pair-parallel insertion sort of LDS-resident runs ----
        for (int i = tid; i < m * NBLK; i += 512) {
            int tt = i >> 9, b2 = i & (NBLK - 1);
            int l = (int)rows[(u + tt + 1) * NBLK + b2] - (int)rows[(u + tt) * NBLK + b2];
            int o = (int)ofs[i];
            for (int k = 1; k < l; ++k) {
                u64 key = sm[o + k];
                int jj = o + k - 1;
                while (jj >= o && sm[jj] > key) { sm[jj + 1] = sm[jj]; --jj; }
                sm[jj + 1] = key;
            }
        }
        __syncthreads();

        // ---- batch-wide emit (lt from cumLoc compares; J coalesced; bits to LDS) ----
        for (int x = tid; x < tot; x += 512) {
            int lt = 0;
            while (lt + 1 < m && x >= cumLoc[u + lt + 1] - aBatch) ++lt;
            u64 rec = sm[x];
            int i_in = x - (cumLoc[u + lt] - aBatch);
            int descpos = N - cumLoc[u + lt + 1] + i_in;
            P[descpos] = expf(__uint_as_float((u32)rec));
            J[aBatch + x] = (u32)(rec >> 33);
            if (rec & 0x100000000ull) {
                int bi = descpos - descbase;
                atomicOr(&bitsSh[bi >> 5], 1u << (bi & 31));
            }
        }
        // binhint for every 256-boundary inside this batch (global bin id)
        {
            int k0 = (aBatch + 255) >> 8;
            int k1e = cumLoc[u + m];
            for (int kk = k0 + tid; (kk << 8) < k1e; kk += 512) {
                int p = kk << 8;
                int lt = 0;
                while (p >= cumLoc[u + lt + 1]) ++lt;
                binhint[kk] = (u16)(t0 + u + lt);
            }
        }
        __syncthreads();

        // ---- flush event bits to global (edge words shared across blocks -> atomicOr) ----
        {
            int nw = (tot + 31) >> 5;
            for (int k = tid; k < nw; k += 512) {
                u32 vv = bitsSh[k];
                if (!vv) continue;
                long gb = (long)descbase + 32l * k;
                int w = (int)(gb >> 5), sh = (int)(gb & 31);
                atomicOr(&E2w[w], vv << sh);
                if (sh && (vv >> (32 - sh))) atomicOr(&E2w[w + 1], vv >> (32 - sh));
            }
        }
        __syncthreads();
        u += m;
    }
}

// ---------------- segment sums: LDS histogram -> COALESCED partials (no global atomics) --
// R8 lesson: 6.7M device-scope atomics = 70 us of serialized RMW (VALUBusy 4.6%, HBM 10%).
// Partials are coalesced streams; reduce_part below does the cross-block sum with 42x
// fewer atomics. 4-way manual unroll gives the loads MLP (R8 VGPR=8 -> zero in flight).
__global__ __launch_bounds__(1024) void sums3(const int* __restrict__ dur,
                                              const float* __restrict__ P,
                                              const u32* __restrict__ E2w,
                                              float* __restrict__ expg_part,
                                              u16* __restrict__ evs_part,
                                              int N, int chunk) {
    __shared__ float he[KSEG];
    __shared__ int hv[KSEG];
    for (int i = threadIdx.x; i < KSEG; i += blockDim.x) { he[i] = 0.f; hv[i] = 0; }
    __syncthreads();
    int b = blockIdx.x;
    int s = b * chunk, e = min(N, s + chunk);
    int j = s + threadIdx.x;
    for (; j + 3072 < e; j += 4096) {
        int d0 = dur[j], d1 = dur[j + 1024], d2 = dur[j + 2048], d3 = dur[j + 3072];
        float p0 = P[j], p1 = P[j + 1024], p2 = P[j + 2048], p3 = P[j + 3072];
        u32 b0 = (E2w[j >> 5] >> (j & 31)) & 1u;
        u32 b1 = (E2w[(j + 1024) >> 5] >> ((j + 1024) & 31)) & 1u;
        u32 b2 = (E2w[(j + 2048) >> 5] >> ((j + 2048) & 31)) & 1u;
        u32 b3 = (E2w[(j + 3072) >> 5] >> ((j + 3072) & 31)) & 1u;
        atomicAdd(&he[d0], p0);
        atomicAdd(&he[d1], p1);
        atomicAdd(&he[d2], p2);
        atomicAdd(&he[d3], p3);
        if (b0) atomicAdd(&hv[d0], 1);
        if (b1) atomicAdd(&hv[d1], 1);
        if (b2) atomicAdd(&hv[d2], 1);
        if (b3) atomicAdd(&hv[d3], 1);
    }
    for (; j < e; j += 1024) {
        int t = dur[j];
        atomicAdd(&he[t], P[j]);
        if ((E2w[j >> 5] >> (j & 31)) & 1u) atomicAdd(&hv[t], 1);
    }
    __syncthreads();
    for (int i = threadIdx.x; i < KSEG; i += blockDim.x) {
        expg_part[(size_t)b * KSEG + i] = he[i];
        evs_part[(size_t)b * KSEG + i] = (u16)hv[i];
    }
}

// ---------------- parallel partial reduction: one wave per (64-bin tile, 64-b tile) ------
// lane owns bin t0+lane; loops RB=64 b-rows with coalesced 256B row loads; ONE atomic per
// (bin, b-tile): 157*8*64*2 = 160K atomics total (vs 6.7M direct).
__global__ __launch_bounds__(64) void reduce_part(const float* __restrict__ expg_part,
                                                  const u16* __restrict__ evs_part,
                                                  float* __restrict__ expg,
                                                  float* __restrict__ evs) {
    int t = blockIdx.x * 64 + threadIdx.x;
    if (t >= KSEG) return;
    int bs = blockIdx.y * RB;
    float a = 0.f;
    int v = 0;
#pragma unroll 4
    for (int b = bs; b < bs + RB; ++b) {
        a += expg_part[(size_t)b * KSEG + t];
        v += (int)evs_part[(size_t)b * KSEG + t];
    }
    if (a != 0.f) atomicAdd(&expg[t], a);
    if (v) atomicAdd(&evs[t], (float)v);
}

// ---------------- risk suffix-sum + baseline hazard + total events (wave-shuffle) --------
__global__ __launch_bounds__(1024) void baseline_kernel(const float* __restrict__ expg,
                                                        const float* __restrict__ evs,
                                                        float* __restrict__ base,
                                                        float* __restrict__ ev_total, int K) {
    __shared__ float fwsum[16];
    __shared__ float carry_s;
    int tid = threadIdx.x, lane = tid & 63, wid = tid >> 6;
    if (tid == 0) carry_s = 0.f;
    float evloc = 0.f;
    __syncthreads();
    for (int b = 0; b < K; b += 1024) {
        int u = b + tid;
        int t = K - 1 - u;
        float h = 0.f, ev = 0.f;
        if (u < K) { h = expg[t]; ev = evs[t]; }
        evloc += ev;
        float v = h;
        for (int off = 1; off < 64; off <<= 1) {
            float x = __shfl_up(v, off);
            if (lane >= off) v += x;
        }
        if (lane == 63) fwsum[wid] = v;
        __syncthreads();
        if (wid == 0) {
            float wv = (lane < 16) ? fwsum[lane] : 0.f;
            for (int off = 1; off < 16; off <<= 1) {
                float x = __shfl_up(wv, off);
                if (lane >= off) wv += x;
            }
            if (lane < 16) fwsum[lane] = wv;
        }
        __syncthreads();
        float risk = v + ((wid > 0) ? fwsum[wid - 1] : 0.f) + carry_s;  // inclusive suffix
        if (u < K) base[t] = (risk > 0.f) ? ev / risk : 0.f;
        __syncthreads();
        if (tid == 1023) carry_s = risk;
    }
    // total events: wave reduce + cross-wave
    for (int off = 32; off > 0; off >>= 1) evloc += __shfl_down(evloc, off);
    __syncthreads();
    if (lane == 0) fwsum[wid] = evloc;
    __syncthreads();
    if (tid == 0) {
        float st = 0.f;
        for (int w = 0; w < 16; ++w) st += fwsum[w];
        ev_total[0] = st;
    }
}

// ---------------- MSE, flat grid-stride: (base[t(i)]*P[i] - E2bit[J[i]])^2 ----------------
__global__ __launch_bounds__(1024) void mse4(const float* __restrict__ P,
                                             const u32* __restrict__ J,
                                             const u32* __restrict__ E2w,
                                             const int* __restrict__ cum,
                                             const u16* __restrict__ binhint,
                                             const float* __restrict__ base,
                                             double* __restrict__ acc, int N) {
    int stride = gridDim.x * blockDim.x;
    double s = 0.0;
    for (int i = blockIdx.x * blockDim.x + threadIdx.x; i < N; i += stride) {
        int t = (int)binhint[i >> 8];
        while (cum[t + 1] <= i) ++t;
        u32 x = J[i];
        float ev = (float)((E2w[x >> 5] >> (x & 31)) & 1u);
        float d = base[t] * P[i] - ev;
        s += (double)d * (double)d;
    }
    __shared__ double sm[1024];
    sm[threadIdx.x] = s;
    __syncthreads();
    for (int o = 512; o > 0; o >>= 1) {
        if ((int)threadIdx.x < o) sm[threadIdx.x] += sm[threadIdx.x + o];
        __syncthreads();
    }
    if (threadIdx.x == 0) atomicAdd(acc, sm[0]);
}

__global__ void final_kernel(const double* __restrict__ acc, const float* __restrict__ ev_total,
                             float* __restrict__ out, int N) {
    out[0] = (ev_total[0] == 0.f) ? 0.0f : (float)(*acc / (double)N);
}

extern "C" void kernel_launch(void* const* d_in, const int* in_sizes, int n_in,
                              void* d_out, int out_size, void* d_ws, size_t ws_size,
                              hipStream_t stream) {
    const float* log_h = (const float*)d_in[0];
    const int* dur     = (const int*)d_in[1];
    const int* events  = (const int*)d_in[2];
    int N = in_sizes[0];
    float* out = (float*)d_out;

    char* ws = (char*)d_ws;
    size_t off = 0;
    auto alloc = [&](size_t bytes) -> char* {
        char* p = ws + off;
        off = (off + bytes + 255) & ~(size_t)255;
        return p;
    };
    // zeroed region: acc + E2w + expg + evs (atomic-accumulated buffers)
    double* acc  = (double*)alloc(8);
    u32*    E2w  = (u32*)alloc(((size_t)N / 32 + 2) * 4);   // event bitfield (desc-indexed)
    float*  expg = (float*)alloc(KSEG * 4);
    float*  evs  = (float*)alloc(KSEG * 4);
    size_t zero_bytes = off;
    float*  ev_total = (float*)alloc(4);
    int*    cum      = (int*)alloc((KSEG + 1) * 4);
    float*  base     = (float*)alloc(KSEG * 4);
    u16*    binhint  = (u16*)alloc(((size_t)N / 256 + 1) * 2);
    u16*    Pb       = (u16*)alloc((size_t)NBLK * (KSEG + 1) * 2);
    u16*    PbT      = (u16*)alloc((size_t)(KSEG + 1) * NBLK * 2);
    u64*    S        = (u64*)alloc((size_t)N * 8);
    float*  P        = (float*)alloc((size_t)N * 4);
    u32*    J        = (u32*)alloc((size_t)N * 4);
    (void)ws_size;

    // sums partials alias S (dead after runsort_ep; mse4 uses P/J, not S)
    float* expg_part = (float*)S;                                     // 20.5 MB
    u16*   evs_part  = (u16*)((char*)S + (size_t)NBLK * KSEG * 4 + 256);  // +10.2 < 64 MB

    int chunk = (N + NBLK - 1) / NBLK;   // 15625 <= CHUNKMAX -> u16 records valid

    hipMemsetAsync(d_ws, 0, zero_bytes, stream);

    localsort_lds<<<NBLK, 1024, 0, stream>>>(dur, log_h, events, S, Pb, N, chunk);
    transpose_pb<<<dim3((KSEG + 64) / 64, NBLK / 64), dim3(64, 4), 0, stream>>>(Pb, PbT);
    cum_rows<<<(KSEG + 4) / 4, 256, 0, stream>>>(PbT, cum);
    runsort_ep<<<(KSEG + GBIN - 1) / GBIN, 512, 0, stream>>>(S, cum, PbT, P, J, E2w,
                                                             binhint, N, chunk);
    sums3<<<NBLK, 1024, 0, stream>>>(dur, P, E2w, expg_part, evs_part, N, chunk);
    reduce_part<<<dim3((KSEG + 63) / 64, NBLK / RB), 64, 0, stream>>>(expg_part, evs_part,
                                                                      expg, evs);
    baseline_kernel<<<1, 1024, 0, stream>>>(expg, evs, base, ev_total, KSEG);
    mse4<<<512, 1024, 0, stream>>>(P, J, E2w, cum, binhint, base, acc, N);
    final_kernel<<<1, 1, 0, stream>>>(acc, ev_total, out, N);
}

// Round 10
// 341.258 us; speedup vs baseline: 1.4953x; 1.0232x over previous
//
#include <hip/hip_runtime.h>

#define KSEG 10000
#define NBLK 512          // sort blocks; chunk = 15628 <= 16384 -> u16 records, 2 blocks/CU
#define CHUNKMAX 16384    // rec16 capacity (14-bit local_j + ev)
#define SWEEPS 4          // 4 sweeps x 4096 (1024 thr x int4) = 16384 coverage
#define GBIN 3            // bins per runsort block (~39 KB LDS -> 4 blocks/CU)
#define CAPE 3072         // runsort staging capacity (3-bin mean 2400, +13 sigma)
#define NXCD 8
#define RB 64             // reduce_part: b-rows per block

typedef unsigned long long u64;
typedef unsigned int u32;
typedef unsigned short u16;
typedef unsigned char u8;

// ---------------- fused: hist + per-block scan + one-phase u16 LDS counting scatter ------
// R9 counters: VGPR=12, VALUBusy 11% -> zero MLP; FETCH had a 32 MB dur re-read.
// Fix: int4-vectorized single input pass (16B/lane) + durations kept in 8 packed u32
// regs (2x14 bits each, statically indexed, fully unrolled -> true VGPRs, no scratch).
// Scatter runs from registers: no global loads after pass 1. launch_bounds(1024,8)
// pins 32 waves/CU (VGPR cap 64) so 2 blocks/CU survive the higher register use.
__global__ __launch_bounds__(1024, 8) void localsort_lds(const int* __restrict__ dur,
                                                         const float* __restrict__ log_h,
                                                         const int* __restrict__ events,
                                                         u64* __restrict__ S,
                                                         u16* __restrict__ Pb,
                                                         int N, int chunk) {
    __shared__ u32 poolA[KSEG];          // 40000 B: h32 (pass1/scan), rec16 (scatter/dump)
    __shared__ u32 cp[KSEG / 2];         // 20000 B packed dual-u16 cursors
    __shared__ u32 wsum[16];
    __shared__ u32 carry_s;
    u32* h32 = poolA;
    u16* rec16 = (u16*)poolA;            // 32768 B < 40000 B, h32 dead before first write

    int b = blockIdx.x;
    int s = b * chunk, e = min(N, s + chunk);
    int tid = threadIdx.x;
    int lane = tid & 63, wid = tid >> 6;

    for (int i = tid; i < KSEG; i += 1024) h32[i] = 0;
    if (tid == 0) carry_s = 0;
    __syncthreads();

    // ---- pass 1 (the ONLY input pass): int4 dur+events, d -> packed regs, histogram ----
    u32 pd[SWEEPS * 2];                  // 2 bins/reg; 0xffff = invalid sentinel
    u32 myev = 0;
#pragma unroll
    for (int w = 0; w < SWEEPS; ++w) {
        int lj = (w << 12) + (tid << 2);
        int j = s + lj;
        int4 dv = make_int4(-1, -1, -1, -1);
        int4 ev = make_int4(0, 0, 0, 0);
        if (j + 3 < e) {
            dv = *(const int4*)(dur + j);       // 16B aligned: chunk % 4 == 0
            ev = *(const int4*)(events + j);
        } else if (j < e) {
            dv.x = dur[j]; ev.x = events[j];
            if (j + 1 < e) { dv.y = dur[j + 1]; ev.y = events[j + 1]; }
            if (j + 2 < e) { dv.z = dur[j + 2]; ev.z = events[j + 2]; }
        }
        if (dv.x >= 0) atomicAdd(&h32[dv.x], 1);
        if (dv.y >= 0) atomicAdd(&h32[dv.y], 1);
        if (dv.z >= 0) atomicAdd(&h32[dv.z], 1);
        if (dv.w >= 0) atomicAdd(&h32[dv.w], 1);
        myev |= (u32)(ev.x & 1) << (w * 4 + 0);
        myev |= (u32)(ev.y & 1) << (w * 4 + 1);
        myev |= (u32)(ev.z & 1) << (w * 4 + 2);
        myev |= (u32)(ev.w & 1) << (w * 4 + 3);
        pd[w * 2]     = (u32)(dv.x & 0xffff) | ((u32)(dv.y & 0xffff) << 16);
        pd[w * 2 + 1] = (u32)(dv.z & 0xffff) | ((u32)(dv.w & 0xffff) << 16);
    }
    __syncthreads();

    // ---- exclusive scan over KSEG bins (strips of 1024, wave-shuffle scan) ----
    for (int base = 0; base < KSEG; base += 1024) {
        int t = base + tid;
        u32 h = (t < KSEG) ? h32[t] : 0;
        u32 v = h;
        for (int off = 1; off < 64; off <<= 1) {
            u32 x = __shfl_up(v, off);
            if (lane >= off) v += x;
        }
        if (lane == 63) wsum[wid] = v;
        __syncthreads();
        if (wid == 0) {
            u32 wv = (lane < 16) ? wsum[lane] : 0;
            for (int off = 1; off < 16; off <<= 1) {
                u32 x = __shfl_up(wv, off);
                if (lane >= off) wv += x;
            }
            if (lane < 16) wsum[lane] = wv;
        }
        __syncthreads();
        u32 incl = v + ((wid > 0) ? wsum[wid - 1] : 0) + carry_s;
        u32 excl = incl - h;
        if (t < KSEG) {
            Pb[(size_t)b * (KSEG + 1) + t] = (u16)excl;
            if (!(t & 1)) cp[t >> 1] = excl | (incl << 16);  // excl_t | excl_{t+1}<<16
        }
        __syncthreads();
        if (tid == 1023) carry_s = incl;
    }
    __syncthreads();
    u32 total = carry_s;
    if (tid == 0) Pb[(size_t)b * (KSEG + 1) + KSEG] = (u16)total;
    __syncthreads();

    // ---- scatter from registers (no global loads) ----
#pragma unroll
    for (int w = 0; w < SWEEPS; ++w) {
#pragma unroll
        for (int c = 0; c < 4; ++c) {
            u32 packed = pd[w * 2 + (c >> 1)];
            int d = (int)((c & 1) ? (packed >> 16) : (packed & 0xffffu));
            if (d != 0xffff) {
                int lj = (w << 12) + (tid << 2) + c;
                u32 add = (d & 1) ? 0x10000u : 1u;
                u32 old = atomicAdd(&cp[d >> 1], add);
                u32 pos = (d & 1) ? (old >> 16) : (old & 0xffffu);
                rec16[pos] = (u16)(((u32)lj << 1) | ((myev >> (w * 4 + c)) & 1u));
            }
        }
    }
    __syncthreads();

    // ---- coalesced dump: reconstruct u64 records; log_h gather in 62.5 KB window ----
    for (u32 i = tid; i < total; i += 1024) {
        u32 v = rec16[i];
        int j = s + (int)(v >> 1);
        u32 hi = ((u32)j << 1) | (v & 1u);
        S[(size_t)s + i] = ((u64)hi << 32) | (u64)__float_as_uint(log_h[j]);
    }
}

// ---------------- transpose Pb[NBLK][K+1] -> PbT[K+1][NBLK] ----------------
__global__ void transpose_pb(const u16* __restrict__ Pb, u16* __restrict__ PbT) {
    __shared__ u16 tile[64][65];
    int t0 = blockIdx.x * 64;
    int b0 = blockIdx.y * 64;
    int tx = threadIdx.x;        // 0..63
    int ty = threadIdx.y;        // 0..3
    for (int r = ty; r < 64; r += 4) {
        int b = b0 + r, t = t0 + tx;
        tile[r][tx] = (b < NBLK && t <= KSEG) ? Pb[(size_t)b * (KSEG + 1) + t] : (u16)0;
    }
    __syncthreads();
    for (int r = ty; r < 64; r += 4) {
        int t = t0 + r, b = b0 + tx;
        if (t <= KSEG && b < NBLK) PbT[(size_t)t * NBLK + b] = tile[tx][r];
    }
}

// ---------------- cum[t] = sum_b Pb[b][t] ----------------
__global__ __launch_bounds__(256) void cum_rows(const u16* __restrict__ PbT,
                                                int* __restrict__ cum) {
    int r = blockIdx.x * 4 + (threadIdx.x >> 6);
    if (r > KSEG) return;
    int lane = threadIdx.x & 63;
    const uint4* row = (const uint4*)(PbT + (size_t)r * NBLK);  // 64 uint4 = 512 u16
    uint4 v = row[lane];
    int sum = (int)(v.x & 0xffff) + (int)(v.x >> 16) + (int)(v.y & 0xffff) + (int)(v.y >> 16)
            + (int)(v.z & 0xffff) + (int)(v.z >> 16) + (int)(v.w & 0xffff) + (int)(v.w >> 16);
    for (int off = 32; off > 0; off >>= 1) sum += __shfl_down(sum, off);
    if (lane == 0) cum[r] = sum;
}

// ---------------- element-parallel runsort, XCD-swizzled + src-major coalesced gather ----
__global__ __launch_bounds__(512, 8) void runsort_ep(const u64* __restrict__ S,
                                                     const int* __restrict__ cum,
                                                     const u16* __restrict__ PbT,
                                                     float* __restrict__ P,
                                                     u32* __restrict__ J,
                                                     u32* __restrict__ E2w,
                                                     u16* __restrict__ binhint,
                                                     int N, int chunk) {
    __shared__ u64 sm[CAPE];                 // 24576 B staging (indexed by asc pos x)
    __shared__ u16 pidy[CAPE];               // 6144 B: gather idx y -> src block bb
    __shared__ u16 ofs[GBIN * NBLK];         // 3072 B: x-space run offsets (tt*NBLK+bb)
    __shared__ u16 rofs[NBLK];               // 1024 B: y-space src-block offsets
    __shared__ u16 rows[(GBIN + 1) * NBLK];  // 4096 B: PbT rows (block-local S offsets)
    __shared__ u32 bitsSh[CAPE / 32];        // 384 B: batch-wide event bits (desc-relative)
    __shared__ u32 wpart[8];
    __shared__ int cumLoc[GBIN + 1];

    // bijective XCD swizzle (nwg = 3334, nwg%8 != 0 -> m204 variant)
    int nwg = (KSEG + GBIN - 1) / GBIN;
    int q = nwg / NXCD, r8 = nwg % NXCD;
    int xcd = blockIdx.x % NXCD, sub = blockIdx.x / NXCD;
    int wg = (xcd < r8 ? xcd * (q + 1) : r8 * (q + 1) + (xcd - r8) * q) + sub;

    int t0 = wg * GBIN;
    int G2 = min(GBIN, KSEG - t0);
    if (G2 <= 0) return;
    int tid = threadIdx.x;
    int lane = tid & 63, wid = tid >> 6;

    for (int i = tid; i < (G2 + 1) * NBLK; i += 512) {
        int t = i >> 9, b = i & (NBLK - 1);
        rows[i] = PbT[(size_t)(t0 + t) * NBLK + b];
    }
    if (tid <= G2) cumLoc[tid] = cum[t0 + tid];
    __syncthreads();

    int u = 0;
    while (u < G2) {
        int m = 1;
        while (u + m < G2 && cumLoc[u + m + 1] - cumLoc[u] <= CAPE) ++m;
        int aBatch = cumLoc[u];
        int tot = cumLoc[u + m] - aBatch;
        int descbase = N - cumLoc[u + m];

        // ---- x-space offsets: run lengths (3/thread chains) + excl scan -> ofs ----
        int base3 = tid * 3;
        int r3[3];
        int sum3 = 0;
        for (int k = 0; k < 3; ++k) {
            int idx = base3 + k;
            int tt = idx >> 9, bb = idx & (NBLK - 1);
            int lk = (tt < m)
                   ? (int)rows[(u + tt + 1) * NBLK + bb] - (int)rows[(u + tt) * NBLK + bb]
                   : 0;
            r3[k] = sum3;
            sum3 += lk;
        }
        int v = sum3;
        for (int off = 1; off < 64; off <<= 1) {
            int x = __shfl_up(v, off);
            if (lane >= off) v += x;
        }
        if (lane == 63) wpart[wid] = (u32)v;
        __syncthreads();
        if (tid == 0) {
            u32 run = 0;
            for (int w = 0; w < 8; ++w) { u32 tmp = wpart[w]; wpart[w] = run; run += tmp; }
        }
        __syncthreads();
        {
            int excl3 = v - sum3 + (int)wpart[wid];
            for (int k = 0; k < 3; ++k) ofs[base3 + k] = (u16)(excl3 + r3[k]);
        }
        __syncthreads();

        // ---- y-space offsets: per-src-block batch range lengths + excl scan -> rofs ----
        int bb = tid;   // 512 threads == NBLK
        int rl = (int)rows[(u + m) * NBLK + bb] - (int)rows[u * NBLK + bb];
        int vy = rl;
        for (int off = 1; off < 64; off <<= 1) {
            int x = __shfl_up(vy, off);
            if (lane >= off) vy += x;
        }
        if (lane == 63) wpart[wid] = (u32)vy;
        __syncthreads();
        if (tid == 0) {
            u32 run = 0;
            for (int w = 0; w < 8; ++w) { u32 tmp = wpart[w]; wpart[w] = run; run += tmp; }
        }
        __syncthreads();
        {
            int excl = vy - rl + (int)wpart[wid];
            rofs[bb] = (u16)excl;
            for (int k = 0; k < rl; ++k) pidy[excl + k] = (u16)bb;  // own range, no sync
        }
        {
            int nw = (tot + 31) >> 5;
            for (int k = tid; k < nw; k += 512) bitsSh[k] = 0;
        }
        __syncthreads();

        // ---- gather, src-major order: consecutive y = consecutive addresses ----
        for (int y = tid; y < tot; y += 512) {
            int b2 = (int)pidy[y];
            int r0 = (int)rows[u * NBLK + b2];
            int r = r0 + (y - (int)rofs[b2]);
            u64 val = S[(size_t)b2 * chunk + r];
            int lt = 0;
            while (lt + 1 < m && r >= (int)rows[(u + lt + 1) * NBLK + b2]) ++lt;
            int x = (int)ofs[lt * NBLK + b2] + (r - (int)rows[(u + lt) * NBLK + b2]);
            sm[x] = val;
        }
        __syncthreads();

        // ---- pair-parallel insertion sort of LDS-resident runs ----
        for (int i = tid; i < m * NBLK; i += 512) {
            int tt = i >> 9, b2 = i & (NBLK - 1);
            int l = (int)rows[(u + tt + 1) * NBLK + b2] - (int)rows[(u + tt) * NBLK + b2];
            int o = (int)ofs[i];
            for (int k = 1; k < l; ++k) {
                u64 key = sm[o + k];
                int jj = o + k - 1;
                while (jj >= o && sm[jj] > key) { sm[jj + 1] = sm[jj]; --jj; }
                sm[jj + 1] = key;
            }
        }
        __syncthreads();

        // ---- batch-wide emit (lt from cumLoc compares; J coalesced; bits to LDS) ----
        for (int x = tid; x < tot; x += 512) {
            int lt = 0;
            while (lt + 1 < m && x >= cumLoc[u + lt + 1] - aBatch) ++lt;
            u64 rec = sm[x];
            int i_in = x - (cumLoc[u + lt] - aBatch);
            int descpos = N - cumLoc[u + lt + 1] + i_in;
            P[descpos] = expf(__uint_as_float((u32)rec));
            J[aBatch + x] = (u32)(rec >> 33);
            if (rec & 0x100000000ull) {
                int bi = descpos - descbase;
                atomicOr(&bitsSh[bi >> 5], 1u << (bi & 31));
            }
        }
        // binhint for every 256-boundary inside this batch (global bin id)
        {
            int k0 = (aBatch + 255) >> 8;
            int k1e = cumLoc[u + m];
            for (int kk = k0 + tid; (kk << 8) < k1e; kk += 512) {
                int p = kk << 8;
                int lt = 0;
                while (p >= cumLoc[u + lt + 1]) ++lt;
                binhint[kk] = (u16)(t0 + u + lt);
            }
        }
        __syncthreads();

        // ---- flush event bits to global (edge words shared across blocks -> atomicOr) ----
        {
            int nw = (tot + 31) >> 5;
            for (int k = tid; k < nw; k += 512) {
                u32 vv = bitsSh[k];
                if (!vv) continue;
                long gb = (long)descbase + 32l * k;
                int w = (int)(gb >> 5), sh = (int)(gb & 31);
                atomicOr(&E2w[w], vv << sh);
                if (sh && (vv >> (32 - sh))) atomicOr(&E2w[w + 1], vv >> (32 - sh));
            }
        }
        __syncthreads();
        u += m;
    }
}

// ---------------- segment sums: LDS histogram -> COALESCED partials (no global atomics) --
__global__ __launch_bounds__(1024) void sums3(const int* __restrict__ dur,
                                              const float* __restrict__ P,
                                              const u32* __restrict__ E2w,
                                              float* __restrict__ expg_part,
                                              u16* __restrict__ evs_part,
                                              int N, int chunk) {
    __shared__ float he[KSEG];
    __shared__ int hv[KSEG];
    for (int i = threadIdx.x; i < KSEG; i += blockDim.x) { he[i] = 0.f; hv[i] = 0; }
    __syncthreads();
    int b = blockIdx.x;
    int s = b * chunk, e = min(N, s + chunk);
    int j = s + threadIdx.x;
    for (; j + 3072 < e; j += 4096) {
        int d0 = dur[j], d1 = dur[j + 1024], d2 = dur[j + 2048], d3 = dur[j + 3072];
        float p0 = P[j], p1 = P[j + 1024], p2 = P[j + 2048], p3 = P[j + 3072];
        u32 b0 = (E2w[j >> 5] >> (j & 31)) & 1u;
        u32 b1 = (E2w[(j + 1024) >> 5] >> ((j + 1024) & 31)) & 1u;
        u32 b2 = (E2w[(j + 2048) >> 5] >> ((j + 2048) & 31)) & 1u;
        u32 b3 = (E2w[(j + 3072) >> 5] >> ((j + 3072) & 31)) & 1u;
        atomicAdd(&he[d0], p0);
        atomicAdd(&he[d1], p1);
        atomicAdd(&he[d2], p2);
        atomicAdd(&he[d3], p3);
        if (b0) atomicAdd(&hv[d0], 1);
        if (b1) atomicAdd(&hv[d1], 1);
        if (b2) atomicAdd(&hv[d2], 1);
        if (b3) atomicAdd(&hv[d3], 1);
    }
    for (; j < e; j += 1024) {
        int t = dur[j];
        atomicAdd(&he[t], P[j]);
        if ((E2w[j >> 5] >> (j & 31)) & 1u) atomicAdd(&hv[t], 1);
    }
    __syncthreads();
    for (int i = threadIdx.x; i < KSEG; i += blockDim.x) {
        expg_part[(size_t)b * KSEG + i] = he[i];
        evs_part[(size_t)b * KSEG + i] = (u16)hv[i];
    }
}

// ---------------- parallel partial reduction: one wave per (64-bin tile, 64-b tile) ------
__global__ __launch_bounds__(64) void reduce_part(const float* __restrict__ expg_part,
                                                  const u16* __restrict__ evs_part,
                                                  float* __restrict__ expg,
                                                  float* __restrict__ evs) {
    int t = blockIdx.x * 64 + threadIdx.x;
    if (t >= KSEG) return;
    int bs = blockIdx.y * RB;
    float a = 0.f;
    int v = 0;
#pragma unroll 4
    for (int b = bs; b < bs + RB; ++b) {
        a += expg_part[(size_t)b * KSEG + t];
        v += (int)evs_part[(size_t)b * KSEG + t];
    }
    if (a != 0.f) atomicAdd(&expg[t], a);
    if (v) atomicAdd(&evs[t], (float)v);
}

// ---------------- risk suffix-sum + baseline hazard + total events (wave-shuffle) --------
__global__ __launch_bounds__(1024) void baseline_kernel(const float* __restrict__ expg,
                                                        const float* __restrict__ evs,
                                                        float* __restrict__ base,
                                                        float* __restrict__ ev_total, int K) {
    __shared__ float fwsum[16];
    __shared__ float carry_s;
    int tid = threadIdx.x, lane = tid & 63, wid = tid >> 6;
    if (tid == 0) carry_s = 0.f;
    float evloc = 0.f;
    __syncthreads();
    for (int b = 0; b < K; b += 1024) {
        int u = b + tid;
        int t = K - 1 - u;
        float h = 0.f, ev = 0.f;
        if (u < K) { h = expg[t]; ev = evs[t]; }
        evloc += ev;
        float v = h;
        for (int off = 1; off < 64; off <<= 1) {
            float x = __shfl_up(v, off);
            if (lane >= off) v += x;
        }
        if (lane == 63) fwsum[wid] = v;
        __syncthreads();
        if (wid == 0) {
            float wv = (lane < 16) ? fwsum[lane] : 0.f;
            for (int off = 1; off < 16; off <<= 1) {
                float x = __shfl_up(wv, off);
                if (lane >= off) wv += x;
            }
            if (lane < 16) fwsum[lane] = wv;
        }
        __syncthreads();
        float risk = v + ((wid > 0) ? fwsum[wid - 1] : 0.f) + carry_s;  // inclusive suffix
        if (u < K) base[t] = (risk > 0.f) ? ev / risk : 0.f;
        __syncthreads();
        if (tid == 1023) carry_s = risk;
    }
    // total events: wave reduce + cross-wave
    for (int off = 32; off > 0; off >>= 1) evloc += __shfl_down(evloc, off);
    __syncthreads();
    if (lane == 0) fwsum[wid] = evloc;
    __syncthreads();
    if (tid == 0) {
        float st = 0.f;
        for (int w = 0; w < 16; ++w) st += fwsum[w];
        ev_total[0] = st;
    }
}

// ---------------- MSE, flat grid-stride: (base[t(i)]*P[i] - E2bit[J[i]])^2 ----------------
__global__ __launch_bounds__(1024) void mse4(const float* __restrict__ P,
                                             const u32* __restrict__ J,
                                             const u32* __restrict__ E2w,
                                             const int* __restrict__ cum,
                                             const u16* __restrict__ binhint,
                                             const float* __restrict__ base,
                                             double* __restrict__ acc, int N) {
    int stride = gridDim.x * blockDim.x;
    double s = 0.0;
    for (int i = blockIdx.x * blockDim.x + threadIdx.x; i < N; i += stride) {
        int t = (int)binhint[i >> 8];
        while (cum[t + 1] <= i) ++t;
        u32 x = J[i];
        float ev = (float)((E2w[x >> 5] >> (x & 31)) & 1u);
        float d = base[t] * P[i] - ev;
        s += (double)d * (double)d;
    }
    __shared__ double sm[1024];
    sm[threadIdx.x] = s;
    __syncthreads();
    for (int o = 512; o > 0; o >>= 1) {
        if ((int)threadIdx.x < o) sm[threadIdx.x] += sm[threadIdx.x + o];
        __syncthreads();
    }
    if (threadIdx.x == 0) atomicAdd(acc, sm[0]);
}

__global__ void final_kernel(const double* __restrict__ acc, const float* __restrict__ ev_total,
                             float* __restrict__ out, int N) {
    out[0] = (ev_total[0] == 0.f) ? 0.0f : (float)(*acc / (double)N);
}

extern "C" void kernel_launch(void* const* d_in, const int* in_sizes, int n_in,
                              void* d_out, int out_size, void* d_ws, size_t ws_size,
                              hipStream_t stream) {
    const float* log_h = (const float*)d_in[0];
    const int* dur     = (const int*)d_in[1];
    const int* events  = (const int*)d_in[2];
    int N = in_sizes[0];
    float* out = (float*)d_out;

    char* ws = (char*)d_ws;
    size_t off = 0;
    auto alloc = [&](size_t bytes) -> char* {
        char* p = ws + off;
        off = (off + bytes + 255) & ~(size_t)255;
        return p;
    };
    // zeroed region: acc + E2w + expg + evs (atomic-accumulated buffers)
    double* acc  = (double*)alloc(8);
    u32*    E2w  = (u32*)alloc(((size_t)N / 32 + 2) * 4);   // event bitfield (desc-indexed)
    float*  expg = (float*)alloc(KSEG * 4);
    float*  evs  = (float*)alloc(KSEG * 4);
    size_t zero_bytes = off;
    float*  ev_total = (float*)alloc(4);
    int*    cum      = (int*)alloc((KSEG + 1) * 4);
    float*  base     = (float*)alloc(KSEG * 4);
    u16*    binhint  = (u16*)alloc(((size_t)N / 256 + 1) * 2);
    u16*    Pb       = (u16*)alloc((size_t)NBLK * (KSEG + 1) * 2);
    u16*    PbT      = (u16*)alloc((size_t)(KSEG + 1) * NBLK * 2);
    u64*    S        = (u64*)alloc(((size_t)NBLK * CHUNKMAX) * 8);  // indexed by b*chunk+i
    float*  P        = (float*)alloc((size_t)N * 4);
    u32*    J        = (u32*)alloc((size_t)N * 4);
    (void)ws_size;

    // sums partials alias S (dead after runsort_ep; mse4 uses P/J, not S)
    float* expg_part = (float*)S;                                     // 20.5 MB
    u16*   evs_part  = (u16*)((char*)S + (size_t)NBLK * KSEG * 4 + 256);  // +10.2 < S size

    int chunk = (((N + NBLK - 1) / NBLK) + 3) & ~3;  // 15628: mult of 4 (int4 align), <= 16384

    hipMemsetAsync(d_ws, 0, zero_bytes, stream);

    localsort_lds<<<NBLK, 1024, 0, stream>>>(dur, log_h, events, S, Pb, N, chunk);
    transpose_pb<<<dim3((KSEG + 64) / 64, NBLK / 64), dim3(64, 4), 0, stream>>>(Pb, PbT);
    cum_rows<<<(KSEG + 4) / 4, 256, 0, stream>>>(PbT, cum);
    runsort_ep<<<(KSEG + GBIN - 1) / GBIN, 512, 0, stream>>>(S, cum, PbT, P, J, E2w,
                                                             binhint, N, chunk);
    sums3<<<NBLK, 1024, 0, stream>>>(dur, P, E2w, expg_part, evs_part, N, chunk);
    reduce_part<<<dim3((KSEG + 63) / 64, NBLK / RB), 64, 0, stream>>>(expg_part, evs_part,
                                                                      expg, evs);
    baseline_kernel<<<1, 1024, 0, stream>>>(expg, evs, base, ev_total, KSEG);
    mse4<<<512, 1024, 0, stream>>>(P, J, E2w, cum, binhint, base, acc, N);
    final_kernel<<<1, 1, 0, stream>>>(acc, ev_total, out, N);
}